// Round 1
// baseline (2404.420 us; speedup 1.0000x reference)
//
#include <hip/hip_runtime.h>

#define NN 100000
#define EE 1250000

// ---------------- weight transpose prep ----------------
// wT layout (floats):
//  [0, 8192)      w1relT  [64][128]  : wT[k*128+o] = w1_rel[o][k]
//  [8192, 16384)  w1rootT [64][128]
//  [16384, 24576) w2relT  [128][64]  : wT[16384+k*64+o] = w2_rel[o][k]
//  [24576, 32768) w2rootT [128][64]
__global__ __launch_bounds__(256) void kprep(const float* __restrict__ w1_rel,
                                             const float* __restrict__ w1_root,
                                             const float* __restrict__ w2_rel,
                                             const float* __restrict__ w2_root,
                                             float* __restrict__ wT) {
  int t = blockIdx.x * 256 + threadIdx.x;
  if (t < 8192) {
    int o = t >> 6, k = t & 63;
    wT[k * 128 + o] = w1_rel[t];
    wT[8192 + k * 128 + o] = w1_root[t];
  } else if (t < 16384) {
    int i = t - 8192;
    int o = i >> 7, k = i & 127;
    wT[16384 + k * 64 + o] = w2_rel[i];
    wT[24576 + k * 64 + o] = w2_root[i];
  }
}

// ---------------- edge scatter-add (64-wide rows, float4 per thread) ----------------
__global__ __launch_bounds__(256) void kscatter(const float* __restrict__ feat,
                                                const int* __restrict__ srcI,
                                                const int* __restrict__ dstI,
                                                float* __restrict__ out) {
  int tid = blockIdx.x * 256 + threadIdx.x;
  int e = tid >> 4;
  if (e >= EE) return;
  int q = tid & 15;
  int s = srcI[e], d = dstI[e];
  const float4 v = *reinterpret_cast<const float4*>(feat + (size_t)s * 64 + (q * 4));
  float* o = out + (size_t)d * 64 + (q * 4);
  atomicAdd(o + 0, v.x);
  atomicAdd(o + 1, v.y);
  atomicAdd(o + 2, v.z);
  atomicAdd(o + 3, v.w);
}

// ---------------- layer 1: h1 = relu(agg1@w1_rel^T + b1 + x@w1_root^T); y = h1@w2_rel^T ----------------
// Block = 256 threads = 4 waves, tile = 64 nodes. lane = node, waves split output channels.
// LDS tiles stored transposed [feature][node] with pad 65 (conflict-free).
__global__ __launch_bounds__(256, 2) void klayer1(
    const float* __restrict__ x, const float* __restrict__ agg,
    const float* __restrict__ wT, const float* __restrict__ b1,
    float* __restrict__ h1, float* __restrict__ y) {
  __shared__ float sm[8320];  // phase A: xsT[64][65] + asT[64][65]; phase B: hT[128][65]; phase C: yT[64][65]
  float* xsT = sm;
  float* asT = sm + 4160;
  int t = threadIdx.x;
  int lane = t & 63;
  int wv = t >> 6;
  int base = blockIdx.x * 64;

  // stage x,agg transposed: coalesced global reads (per wave: fixed node, k=lane)
  for (int i = t; i < 4096; i += 256) {
    int n = i >> 6, k = i & 63;
    int node = base + n;
    float xv = 0.f, av = 0.f;
    if (node < NN) {
      xv = x[(size_t)node * 64 + k];
      av = agg[(size_t)node * 64 + k];
    }
    xsT[k * 65 + n] = xv;
    asT[k * 65 + n] = av;
  }
  __syncthreads();

  // GEMM 1: wave wv computes outs [wv*32, wv*32+32)
  int o0 = __builtin_amdgcn_readfirstlane(wv * 32);
  const float* wrelT = wT;
  const float* wrootT = wT + 8192;
  float acc[32];
#pragma unroll
  for (int o = 0; o < 32; ++o) acc[o] = 0.f;
  for (int k = 0; k < 64; ++k) {
    float av = asT[k * 65 + lane];
    float xv = xsT[k * 65 + lane];
    const float* wr = wrelT + k * 128 + o0;   // wave-uniform -> s_load
    const float* wo = wrootT + k * 128 + o0;
#pragma unroll
    for (int o = 0; o < 32; ++o) acc[o] += av * wr[o] + xv * wo[o];
  }
  __syncthreads();
  // hT[o][n] = relu(acc + b1)
#pragma unroll
  for (int o = 0; o < 32; ++o)
    sm[(o0 + o) * 65 + lane] = fmaxf(acc[o] + b1[o0 + o], 0.f);
  __syncthreads();

  // store h1 (coalesced via LDS)
  for (int i = t; i < 8192; i += 256) {
    int n = i >> 7, o = i & 127;
    int node = base + n;
    if (node < NN) h1[(size_t)node * 128 + o] = sm[o * 65 + n];
  }

  // GEMM 2 (fused): y = h1 @ w2_rel^T, wave wv computes outs [wv*16, wv*16+16)
  int p0 = __builtin_amdgcn_readfirstlane(wv * 16);
  const float* w2relT = wT + 16384;
  float acc2[16];
#pragma unroll
  for (int o = 0; o < 16; ++o) acc2[o] = 0.f;
  for (int k = 0; k < 128; ++k) {
    float hv = sm[k * 65 + lane];
    const float* w = w2relT + k * 64 + p0;
#pragma unroll
    for (int o = 0; o < 16; ++o) acc2[o] += hv * w[o];
  }
  __syncthreads();
#pragma unroll
  for (int o = 0; o < 16; ++o) sm[(p0 + o) * 65 + lane] = acc2[o];
  __syncthreads();
  for (int i = t; i < 4096; i += 256) {
    int n = i >> 6, o = i & 63;
    int node = base + n;
    if (node < NN) y[(size_t)node * 64 + o] = sm[o * 65 + n];
  }
}

// ---------------- layer 2 + pooling: h2 = relu(agg2y + b2 + h1@w2_root^T); pool += h2 ----------------
__global__ __launch_bounds__(256, 2) void klayer2(
    const float* __restrict__ h1, const float* __restrict__ aggy,
    const float* __restrict__ wT, const float* __restrict__ b2,
    const int* __restrict__ batch, float* __restrict__ pool,
    float* __restrict__ cnt) {
  __shared__ float sm[8320];  // h1T[128][65]
  __shared__ float aT[4160];  // aggyT[64][65]
  __shared__ float pl[4096];  // block-local pool [64 graphs][64 ch]
  __shared__ float cl[64];
  int t = threadIdx.x;
  int lane = t & 63;
  int wv = t >> 6;
  int base = blockIdx.x * 64;

  for (int i = t; i < 8192; i += 256) {
    int n = i >> 7, k = i & 127;
    int node = base + n;
    sm[k * 65 + n] = (node < NN) ? h1[(size_t)node * 128 + k] : 0.f;
  }
  for (int i = t; i < 4096; i += 256) {
    int n = i >> 6, o = i & 63;
    int node = base + n;
    aT[o * 65 + n] = (node < NN) ? aggy[(size_t)node * 64 + o] : 0.f;
    pl[i] = 0.f;
  }
  if (t < 64) cl[t] = 0.f;
  __syncthreads();

  int p0 = __builtin_amdgcn_readfirstlane(wv * 16);
  const float* w2rootT = wT + 24576;
  float acc[16];
#pragma unroll
  for (int o = 0; o < 16; ++o) acc[o] = 0.f;
  for (int k = 0; k < 128; ++k) {
    float hv = sm[k * 65 + lane];
    const float* w = w2rootT + k * 64 + p0;
#pragma unroll
    for (int o = 0; o < 16; ++o) acc[o] += hv * w[o];
  }

  int node = base + lane;
  if (node < NN) {
    int g = batch[node];
#pragma unroll
    for (int o = 0; o < 16; ++o) {
      float v = fmaxf(acc[o] + aT[(p0 + o) * 65 + lane] + b2[p0 + o], 0.f);
      atomicAdd(&pl[g * 64 + p0 + o], v);
    }
    if (wv == 0) atomicAdd(&cl[g], 1.f);
  }
  __syncthreads();

  for (int i = t; i < 4096; i += 256) {
    float v = pl[i];
    if (v != 0.f) atomicAdd(&pool[i], v);
  }
  if (t < 64) {
    float c = cl[t];
    if (c != 0.f) atomicAdd(&cnt[t], c);
  }
}

// ---------------- pooled MLPs ----------------
__global__ void kfinal(const float* __restrict__ pool, const float* __restrict__ cnt,
                       const float* __restrict__ es_w1, const float* __restrict__ es_b1,
                       const float* __restrict__ es_w2, const float* __restrict__ es_b2,
                       const float* __restrict__ es_w3, const float* __restrict__ es_b3,
                       const float* __restrict__ d_w1, const float* __restrict__ d_b1,
                       const float* __restrict__ d_w2, const float* __restrict__ d_b2,
                       const float* __restrict__ d_w3, const float* __restrict__ d_b3,
                       float* __restrict__ out) {
  int g = threadIdx.x;
  if (g >= 64) return;
  float c = fmaxf(cnt[g], 1.f);
  float h3[64];
#pragma unroll
  for (int o = 0; o < 64; ++o) {
    h3[o] = pool[g * 64 + o] / c;
    out[g * 64 + o] = h3[o];
  }
  float z1[8];
#pragma unroll
  for (int j = 0; j < 8; ++j) {
    float a = es_b1[j];
#pragma unroll
    for (int k = 0; k < 64; ++k) a += es_w1[j * 64 + k] * h3[k];
    z1[j] = fmaxf(a, 0.f);
  }
  float z2[4];
#pragma unroll
  for (int j = 0; j < 4; ++j) {
    float a = es_b2[j];
#pragma unroll
    for (int k = 0; k < 8; ++k) a += es_w2[j * 8 + k] * z1[k];
    z2[j] = fmaxf(a, 0.f);
  }
  float z = es_b3[0];
#pragma unroll
  for (int k = 0; k < 4; ++k) z += es_w3[k] * z2[k];
  float t1[4];
#pragma unroll
  for (int j = 0; j < 4; ++j) t1[j] = fmaxf(d_w1[j] * z + d_b1[j], 0.f);
  float t2[8];
#pragma unroll
  for (int j = 0; j < 8; ++j) {
    float a = d_b2[j];
#pragma unroll
    for (int k = 0; k < 4; ++k) a += d_w2[j * 4 + k] * t1[k];
    t2[j] = fmaxf(a, 0.f);
  }
#pragma unroll
  for (int o = 0; o < 64; ++o) {
    float a = d_b3[o];
#pragma unroll
    for (int k = 0; k < 8; ++k) a += d_w3[o * 8 + k] * t2[k];
    out[4096 + g * 64 + o] = a;
  }
}

extern "C" void kernel_launch(void* const* d_in, const int* in_sizes, int n_in,
                              void* d_out, int out_size, void* d_ws, size_t ws_size,
                              hipStream_t stream) {
  const float* x = (const float*)d_in[0];
  const int* ei = (const int*)d_in[1];
  const int* srcI = ei;
  const int* dstI = ei + EE;
  const int* batch = (const int*)d_in[2];
  const float* w1_rel = (const float*)d_in[3];
  const float* b1_rel = (const float*)d_in[4];
  const float* w1_root = (const float*)d_in[5];
  const float* w2_rel = (const float*)d_in[6];
  const float* b2_rel = (const float*)d_in[7];
  const float* w2_root = (const float*)d_in[8];
  const float* es_w1 = (const float*)d_in[9];
  const float* es_b1 = (const float*)d_in[10];
  const float* es_w2 = (const float*)d_in[11];
  const float* es_b2 = (const float*)d_in[12];
  const float* es_w3 = (const float*)d_in[13];
  const float* es_b3 = (const float*)d_in[14];
  const float* d_w1 = (const float*)d_in[15];
  const float* d_b1 = (const float*)d_in[16];
  const float* d_w2 = (const float*)d_in[17];
  const float* d_b2 = (const float*)d_in[18];
  const float* d_w3 = (const float*)d_in[19];
  const float* d_b3 = (const float*)d_in[20];

  float* ws = (float*)d_ws;
  float* agg = ws;                          // N*64 (agg1, then reused as agg2y)
  float* h1 = ws + (size_t)NN * 64;         // N*128
  float* y = ws + (size_t)NN * 192;         // N*64
  float* pool = ws + (size_t)NN * 256;      // 4096
  float* cntp = pool + 4096;                // 64
  float* wT = cntp + 64;                    // 32768
  float* out = (float*)d_out;

  hipMemsetAsync(agg, 0, (size_t)NN * 64 * 4, stream);
  hipMemsetAsync(pool, 0, (4096 + 64) * 4, stream);
  kprep<<<64, 256, 0, stream>>>(w1_rel, w1_root, w2_rel, w2_root, wT);
  kscatter<<<(EE * 16) / 256, 256, 0, stream>>>(x, srcI, dstI, agg);
  klayer1<<<(NN + 63) / 64, 256, 0, stream>>>(x, agg, wT, b1_rel, h1, y);
  hipMemsetAsync(agg, 0, (size_t)NN * 64 * 4, stream);
  kscatter<<<(EE * 16) / 256, 256, 0, stream>>>(y, srcI, dstI, agg);
  klayer2<<<(NN + 63) / 64, 256, 0, stream>>>(h1, agg, wT, b2_rel, batch, pool, cntp);
  kfinal<<<1, 64, 0, stream>>>(pool, cntp, es_w1, es_b1, es_w2, es_b2, es_w3, es_b3,
                               d_w1, d_b1, d_w2, d_b2, d_w3, d_b3, out);
}

// Round 2
// 682.364 us; speedup vs baseline: 3.5237x; 3.5237x over previous
//
#include <hip/hip_runtime.h>

#define NN 100000
#define EE 1250000

// ---------------- weight transpose prep ----------------
// wT layout (floats):
//  [0, 8192)      w1relT  [64][128]  : wT[k*128+o] = w1_rel[o][k]
//  [8192, 16384)  w1rootT [64][128]
//  [16384, 24576) w2relT  [128][64]  : wT[16384+k*64+o] = w2_rel[o][k]
//  [24576, 32768) w2rootT [128][64]
__global__ __launch_bounds__(256) void kprep(const float* __restrict__ w1_rel,
                                             const float* __restrict__ w1_root,
                                             const float* __restrict__ w2_rel,
                                             const float* __restrict__ w2_root,
                                             float* __restrict__ wT) {
  int t = blockIdx.x * 256 + threadIdx.x;
  if (t < 8192) {
    int o = t >> 6, k = t & 63;
    wT[k * 128 + o] = w1_rel[t];
    wT[8192 + k * 128 + o] = w1_root[t];
  } else if (t < 16384) {
    int i = t - 8192;
    int o = i >> 7, k = i & 127;
    wT[16384 + k * 64 + o] = w2_rel[i];
    wT[24576 + k * 64 + o] = w2_root[i];
  }
}

// ---------------- CSR build: count / scan / fill ----------------
__global__ __launch_bounds__(256) void kcount(const int* __restrict__ dstI,
                                              int* __restrict__ counts) {
  int e = blockIdx.x * 256 + threadIdx.x;
  if (e < EE) atomicAdd(&counts[dstI[e]], 1);
}

__global__ __launch_bounds__(1024) void kscan(const int* __restrict__ counts,
                                              int* __restrict__ starts) {
  __shared__ int part[1024];
  int t = threadIdx.x;
  const int CH = (NN + 1023) / 1024;  // 98
  int lo = t * CH;
  int hi = lo + CH; if (hi > NN) hi = NN; if (lo > NN) lo = NN;
  int s = 0;
  for (int i = lo; i < hi; ++i) s += counts[i];
  part[t] = s;
  __syncthreads();
  if (t == 0) {
    int run = 0;
    for (int i = 0; i < 1024; ++i) { int v = part[i]; part[i] = run; run += v; }
  }
  __syncthreads();
  int run = part[t];
  for (int i = lo; i < hi; ++i) { starts[i] = run; run += counts[i]; }
  if (t == 1023) starts[NN] = EE;
}

__global__ __launch_bounds__(256) void kfill(const int* __restrict__ srcI,
                                             const int* __restrict__ dstI,
                                             const int* __restrict__ starts,
                                             int* __restrict__ cursor,
                                             int* __restrict__ esrc) {
  int e = blockIdx.x * 256 + threadIdx.x;
  if (e >= EE) return;
  int d = dstI[e];
  int pos = starts[d] + atomicAdd(&cursor[d], 1);
  esrc[pos] = srcI[e];
}

// ---------------- CSR gather aggregation: out[n] = sum_{e in CSR[n]} feat[src(e)] ----------------
// One wave per node; lane = channel. Row loads are 256B coalesced, served from L3.
__global__ __launch_bounds__(256) void kgather(const float* __restrict__ feat,
                                               const int* __restrict__ starts,
                                               const int* __restrict__ esrc,
                                               float* __restrict__ out) {
  int w = (blockIdx.x * 256 + threadIdx.x) >> 6;  // node
  int lane = threadIdx.x & 63;
  if (w >= NN) return;
  int b = starts[w], e = starts[w + 1];
  float acc = 0.f;
  int i = b;
  for (; i + 4 <= e; i += 4) {
    int s0 = __builtin_amdgcn_readfirstlane(esrc[i]);
    int s1 = __builtin_amdgcn_readfirstlane(esrc[i + 1]);
    int s2 = __builtin_amdgcn_readfirstlane(esrc[i + 2]);
    int s3 = __builtin_amdgcn_readfirstlane(esrc[i + 3]);
    float v0 = feat[(size_t)s0 * 64 + lane];
    float v1 = feat[(size_t)s1 * 64 + lane];
    float v2 = feat[(size_t)s2 * 64 + lane];
    float v3 = feat[(size_t)s3 * 64 + lane];
    acc += (v0 + v1) + (v2 + v3);
  }
  for (; i < e; ++i) {
    int s = __builtin_amdgcn_readfirstlane(esrc[i]);
    acc += feat[(size_t)s * 64 + lane];
  }
  out[(size_t)w * 64 + lane] = acc;
}

// ---------------- layer 1: h1 = relu(agg1@w1_rel^T + b1 + x@w1_root^T); y = h1@w2_rel^T ----------------
__global__ __launch_bounds__(256, 2) void klayer1(
    const float* __restrict__ x, const float* __restrict__ agg,
    const float* __restrict__ wT, const float* __restrict__ b1,
    float* __restrict__ h1, float* __restrict__ y) {
  __shared__ float sm[8320];
  float* xsT = sm;
  float* asT = sm + 4160;
  int t = threadIdx.x;
  int lane = t & 63;
  int wv = t >> 6;
  int base = blockIdx.x * 64;

  for (int i = t; i < 4096; i += 256) {
    int n = i >> 6, k = i & 63;
    int node = base + n;
    float xv = 0.f, av = 0.f;
    if (node < NN) {
      xv = x[(size_t)node * 64 + k];
      av = agg[(size_t)node * 64 + k];
    }
    xsT[k * 65 + n] = xv;
    asT[k * 65 + n] = av;
  }
  __syncthreads();

  int o0 = __builtin_amdgcn_readfirstlane(wv * 32);
  const float* wrelT = wT;
  const float* wrootT = wT + 8192;
  float acc[32];
#pragma unroll
  for (int o = 0; o < 32; ++o) acc[o] = 0.f;
  for (int k = 0; k < 64; ++k) {
    float av = asT[k * 65 + lane];
    float xv = xsT[k * 65 + lane];
    const float* wr = wrelT + k * 128 + o0;
    const float* wo = wrootT + k * 128 + o0;
#pragma unroll
    for (int o = 0; o < 32; ++o) acc[o] += av * wr[o] + xv * wo[o];
  }
  __syncthreads();
#pragma unroll
  for (int o = 0; o < 32; ++o)
    sm[(o0 + o) * 65 + lane] = fmaxf(acc[o] + b1[o0 + o], 0.f);
  __syncthreads();

  for (int i = t; i < 8192; i += 256) {
    int n = i >> 7, o = i & 127;
    int node = base + n;
    if (node < NN) h1[(size_t)node * 128 + o] = sm[o * 65 + n];
  }

  int p0 = __builtin_amdgcn_readfirstlane(wv * 16);
  const float* w2relT = wT + 16384;
  float acc2[16];
#pragma unroll
  for (int o = 0; o < 16; ++o) acc2[o] = 0.f;
  for (int k = 0; k < 128; ++k) {
    float hv = sm[k * 65 + lane];
    const float* w = w2relT + k * 64 + p0;
#pragma unroll
    for (int o = 0; o < 16; ++o) acc2[o] += hv * w[o];
  }
  __syncthreads();
#pragma unroll
  for (int o = 0; o < 16; ++o) sm[(p0 + o) * 65 + lane] = acc2[o];
  __syncthreads();
  for (int i = t; i < 4096; i += 256) {
    int n = i >> 6, o = i & 63;
    int node = base + n;
    if (node < NN) y[(size_t)node * 64 + o] = sm[o * 65 + n];
  }
}

// ---------------- layer 2 + pooling ----------------
__global__ __launch_bounds__(256, 2) void klayer2(
    const float* __restrict__ h1, const float* __restrict__ aggy,
    const float* __restrict__ wT, const float* __restrict__ b2,
    const int* __restrict__ batch, float* __restrict__ pool,
    float* __restrict__ cnt) {
  __shared__ float sm[8320];
  __shared__ float aT[4160];
  __shared__ float pl[4096];
  __shared__ float cl[64];
  int t = threadIdx.x;
  int lane = t & 63;
  int wv = t >> 6;
  int base = blockIdx.x * 64;

  for (int i = t; i < 8192; i += 256) {
    int n = i >> 7, k = i & 127;
    int node = base + n;
    sm[k * 65 + n] = (node < NN) ? h1[(size_t)node * 128 + k] : 0.f;
  }
  for (int i = t; i < 4096; i += 256) {
    int n = i >> 6, o = i & 63;
    int node = base + n;
    aT[o * 65 + n] = (node < NN) ? aggy[(size_t)node * 64 + o] : 0.f;
    pl[i] = 0.f;
  }
  if (t < 64) cl[t] = 0.f;
  __syncthreads();

  int p0 = __builtin_amdgcn_readfirstlane(wv * 16);
  const float* w2rootT = wT + 24576;
  float acc[16];
#pragma unroll
  for (int o = 0; o < 16; ++o) acc[o] = 0.f;
  for (int k = 0; k < 128; ++k) {
    float hv = sm[k * 65 + lane];
    const float* w = w2rootT + k * 64 + p0;
#pragma unroll
    for (int o = 0; o < 16; ++o) acc[o] += hv * w[o];
  }

  int node = base + lane;
  if (node < NN) {
    int g = batch[node];
#pragma unroll
    for (int o = 0; o < 16; ++o) {
      float v = fmaxf(acc[o] + aT[(p0 + o) * 65 + lane] + b2[p0 + o], 0.f);
      atomicAdd(&pl[g * 64 + p0 + o], v);
    }
    if (wv == 0) atomicAdd(&cl[g], 1.f);
  }
  __syncthreads();

  for (int i = t; i < 4096; i += 256) {
    float v = pl[i];
    if (v != 0.f) atomicAdd(&pool[i], v);
  }
  if (t < 64) {
    float c = cl[t];
    if (c != 0.f) atomicAdd(&cnt[t], c);
  }
}

// ---------------- pooled MLPs ----------------
__global__ void kfinal(const float* __restrict__ pool, const float* __restrict__ cnt,
                       const float* __restrict__ es_w1, const float* __restrict__ es_b1,
                       const float* __restrict__ es_w2, const float* __restrict__ es_b2,
                       const float* __restrict__ es_w3, const float* __restrict__ es_b3,
                       const float* __restrict__ d_w1, const float* __restrict__ d_b1,
                       const float* __restrict__ d_w2, const float* __restrict__ d_b2,
                       const float* __restrict__ d_w3, const float* __restrict__ d_b3,
                       float* __restrict__ out) {
  int g = threadIdx.x;
  if (g >= 64) return;
  float c = fmaxf(cnt[g], 1.f);
  float h3[64];
#pragma unroll
  for (int o = 0; o < 64; ++o) {
    h3[o] = pool[g * 64 + o] / c;
    out[g * 64 + o] = h3[o];
  }
  float z1[8];
#pragma unroll
  for (int j = 0; j < 8; ++j) {
    float a = es_b1[j];
#pragma unroll
    for (int k = 0; k < 64; ++k) a += es_w1[j * 64 + k] * h3[k];
    z1[j] = fmaxf(a, 0.f);
  }
  float z2[4];
#pragma unroll
  for (int j = 0; j < 4; ++j) {
    float a = es_b2[j];
#pragma unroll
    for (int k = 0; k < 8; ++k) a += es_w2[j * 8 + k] * z1[k];
    z2[j] = fmaxf(a, 0.f);
  }
  float z = es_b3[0];
#pragma unroll
  for (int k = 0; k < 4; ++k) z += es_w3[k] * z2[k];
  float t1[4];
#pragma unroll
  for (int j = 0; j < 4; ++j) t1[j] = fmaxf(d_w1[j] * z + d_b1[j], 0.f);
  float t2[8];
#pragma unroll
  for (int j = 0; j < 8; ++j) {
    float a = d_b2[j];
#pragma unroll
    for (int k = 0; k < 4; ++k) a += d_w2[j * 4 + k] * t1[k];
    t2[j] = fmaxf(a, 0.f);
  }
#pragma unroll
  for (int o = 0; o < 64; ++o) {
    float a = d_b3[o];
#pragma unroll
    for (int k = 0; k < 8; ++k) a += d_w3[o * 8 + k] * t2[k];
    out[4096 + g * 64 + o] = a;
  }
}

extern "C" void kernel_launch(void* const* d_in, const int* in_sizes, int n_in,
                              void* d_out, int out_size, void* d_ws, size_t ws_size,
                              hipStream_t stream) {
  const float* x = (const float*)d_in[0];
  const int* ei = (const int*)d_in[1];
  const int* srcI = ei;
  const int* dstI = ei + EE;
  const int* batch = (const int*)d_in[2];
  const float* w1_rel = (const float*)d_in[3];
  const float* b1_rel = (const float*)d_in[4];
  const float* w1_root = (const float*)d_in[5];
  const float* w2_rel = (const float*)d_in[6];
  const float* b2_rel = (const float*)d_in[7];
  const float* w2_root = (const float*)d_in[8];
  const float* es_w1 = (const float*)d_in[9];
  const float* es_b1 = (const float*)d_in[10];
  const float* es_w2 = (const float*)d_in[11];
  const float* es_b2 = (const float*)d_in[12];
  const float* es_w3 = (const float*)d_in[13];
  const float* es_b3 = (const float*)d_in[14];
  const float* d_w1 = (const float*)d_in[15];
  const float* d_b1 = (const float*)d_in[16];
  const float* d_w2 = (const float*)d_in[17];
  const float* d_b2 = (const float*)d_in[18];
  const float* d_w3 = (const float*)d_in[19];
  const float* d_b3 = (const float*)d_in[20];

  float* ws = (float*)d_ws;
  float* agg = ws;                          // N*64 (agg1, reused as agg2y)
  float* h1 = ws + (size_t)NN * 64;         // N*128
  float* y = ws + (size_t)NN * 192;         // N*64
  float* pool = ws + (size_t)NN * 256;      // 4096
  float* cntp = pool + 4096;                // 64
  float* wT = cntp + 64;                    // 32768
  int* counts = (int*)(wT + 32768);         // NN
  int* starts = counts + NN;                // NN+1
  int* cursor = starts + NN + 1;            // NN
  int* esrc = cursor + NN;                  // EE
  float* out = (float*)d_out;

  hipMemsetAsync(pool, 0, (4096 + 64) * 4, stream);
  hipMemsetAsync(counts, 0, (size_t)NN * 4, stream);
  hipMemsetAsync(cursor, 0, (size_t)NN * 4, stream);
  kprep<<<64, 256, 0, stream>>>(w1_rel, w1_root, w2_rel, w2_root, wT);
  kcount<<<(EE + 255) / 256, 256, 0, stream>>>(dstI, counts);
  kscan<<<1, 1024, 0, stream>>>(counts, starts);
  kfill<<<(EE + 255) / 256, 256, 0, stream>>>(srcI, dstI, starts, cursor, esrc);
  kgather<<<(NN * 64 + 255) / 256, 256, 0, stream>>>(x, starts, esrc, agg);
  klayer1<<<(NN + 63) / 64, 256, 0, stream>>>(x, agg, wT, b1_rel, h1, y);
  kgather<<<(NN * 64 + 255) / 256, 256, 0, stream>>>(y, starts, esrc, agg);
  klayer2<<<(NN + 63) / 64, 256, 0, stream>>>(h1, agg, wT, b2_rel, batch, pool, cntp);
  kfinal<<<1, 64, 0, stream>>>(pool, cntp, es_w1, es_b1, es_w2, es_b2, es_w3, es_b3,
                               d_w1, d_b1, d_w2, d_b2, d_w3, d_b3, out);
}

// Round 3
// 530.801 us; speedup vs baseline: 4.5298x; 1.2855x over previous
//
#include <hip/hip_runtime.h>

#define NN 100000
#define EE 1250000
#define SCAN_NB ((NN + 255) / 256)  // 391

// ---------------- weight transpose prep ----------------
// wT layout (floats):
//  [0, 8192)      w1relT  [64][128]  : wT[k*128+o] = w1_rel[o][k]
//  [8192, 16384)  w1rootT [64][128]
//  [16384, 24576) w2relT  [128][64]  : wT[16384+k*64+o] = w2_rel[o][k]
//  [24576, 32768) w2rootT [128][64]
__global__ __launch_bounds__(256) void kprep(const float* __restrict__ w1_rel,
                                             const float* __restrict__ w1_root,
                                             const float* __restrict__ w2_rel,
                                             const float* __restrict__ w2_root,
                                             float* __restrict__ wT) {
  int t = blockIdx.x * 256 + threadIdx.x;
  if (t < 8192) {
    int o = t >> 6, k = t & 63;
    wT[k * 128 + o] = w1_rel[t];
    wT[8192 + k * 128 + o] = w1_root[t];
  } else if (t < 16384) {
    int i = t - 8192;
    int o = i >> 7, k = i & 127;
    wT[16384 + k * 64 + o] = w2_rel[i];
    wT[24576 + k * 64 + o] = w2_root[i];
  }
}

// ---------------- CSR build: count / 3-phase scan / fill ----------------
__global__ __launch_bounds__(256) void kcount(const int* __restrict__ dstI,
                                              int* __restrict__ counts) {
  int e = blockIdx.x * 256 + threadIdx.x;
  if (e < EE) atomicAdd(&counts[dstI[e]], 1);
}

// per-block sums of counts
__global__ __launch_bounds__(256) void kscanA(const int* __restrict__ counts,
                                              int* __restrict__ bsum) {
  __shared__ int red[256];
  int t = threadIdx.x;
  int i = blockIdx.x * 256 + t;
  red[t] = (i < NN) ? counts[i] : 0;
  __syncthreads();
  for (int s = 128; s > 0; s >>= 1) {
    if (t < s) red[t] += red[t + s];
    __syncthreads();
  }
  if (t == 0) bsum[blockIdx.x] = red[0];
}

// single-block exclusive scan of SCAN_NB block sums
__global__ __launch_bounds__(512) void kscanB(const int* __restrict__ bsum,
                                              int* __restrict__ boff) {
  __shared__ int sm[512];
  int t = threadIdx.x;
  int v = (t < SCAN_NB) ? bsum[t] : 0;
  sm[t] = v;
  __syncthreads();
  for (int d = 1; d < 512; d <<= 1) {
    int u = (t >= d) ? sm[t - d] : 0;
    __syncthreads();
    sm[t] += u;
    __syncthreads();
  }
  if (t < SCAN_NB) boff[t] = sm[t] - v;  // exclusive
}

// per-block local exclusive scan + global offset; writes starts AND cursor
__global__ __launch_bounds__(256) void kscanC(const int* __restrict__ counts,
                                              const int* __restrict__ boff,
                                              int* __restrict__ starts,
                                              int* __restrict__ cursor) {
  __shared__ int sm[256];
  int t = threadIdx.x;
  int i = blockIdx.x * 256 + t;
  int v = (i < NN) ? counts[i] : 0;
  sm[t] = v;
  __syncthreads();
  for (int d = 1; d < 256; d <<= 1) {
    int u = (t >= d) ? sm[t - d] : 0;
    __syncthreads();
    sm[t] += u;
    __syncthreads();
  }
  int ex = sm[t] - v + boff[blockIdx.x];
  if (i < NN) {
    starts[i] = ex;
    cursor[i] = ex;
  }
  if (i == NN - 1) starts[NN] = EE;
}

__global__ __launch_bounds__(256) void kfill(const int* __restrict__ srcI,
                                             const int* __restrict__ dstI,
                                             int* __restrict__ cursor,
                                             int* __restrict__ esrc) {
  int e = blockIdx.x * 256 + threadIdx.x;
  if (e >= EE) return;
  int d = dstI[e];
  int pos = atomicAdd(&cursor[d], 1);
  esrc[pos] = srcI[e];
}

// ---------------- CSR gather aggregation: out[n] = sum_{e in CSR[n]} feat[src(e)] ----------------
__global__ __launch_bounds__(256) void kgather(const float* __restrict__ feat,
                                               const int* __restrict__ starts,
                                               const int* __restrict__ esrc,
                                               float* __restrict__ out) {
  int w = (blockIdx.x * 256 + threadIdx.x) >> 6;  // node
  int lane = threadIdx.x & 63;
  if (w >= NN) return;
  int b = starts[w], e = starts[w + 1];
  float acc = 0.f;
  int i = b;
  for (; i + 4 <= e; i += 4) {
    int s0 = __builtin_amdgcn_readfirstlane(esrc[i]);
    int s1 = __builtin_amdgcn_readfirstlane(esrc[i + 1]);
    int s2 = __builtin_amdgcn_readfirstlane(esrc[i + 2]);
    int s3 = __builtin_amdgcn_readfirstlane(esrc[i + 3]);
    float v0 = feat[(size_t)s0 * 64 + lane];
    float v1 = feat[(size_t)s1 * 64 + lane];
    float v2 = feat[(size_t)s2 * 64 + lane];
    float v3 = feat[(size_t)s3 * 64 + lane];
    acc += (v0 + v1) + (v2 + v3);
  }
  for (; i < e; ++i) {
    int s = __builtin_amdgcn_readfirstlane(esrc[i]);
    acc += feat[(size_t)s * 64 + lane];
  }
  out[(size_t)w * 64 + lane] = acc;
}

// ---------------- layer 1: h1 = relu(agg1@w1_rel^T + b1 + x@w1_root^T); y = h1@w2_rel^T ----------------
__global__ __launch_bounds__(256, 2) void klayer1(
    const float* __restrict__ x, const float* __restrict__ agg,
    const float* __restrict__ wT, const float* __restrict__ b1,
    float* __restrict__ h1, float* __restrict__ y) {
  __shared__ float sm[8320];
  float* xsT = sm;
  float* asT = sm + 4160;
  int t = threadIdx.x;
  int lane = t & 63;
  int wv = t >> 6;
  int base = blockIdx.x * 64;

  for (int i = t; i < 4096; i += 256) {
    int n = i >> 6, k = i & 63;
    int node = base + n;
    float xv = 0.f, av = 0.f;
    if (node < NN) {
      xv = x[(size_t)node * 64 + k];
      av = agg[(size_t)node * 64 + k];
    }
    xsT[k * 65 + n] = xv;
    asT[k * 65 + n] = av;
  }
  __syncthreads();

  int o0 = __builtin_amdgcn_readfirstlane(wv * 32);
  const float* wrelT = wT;
  const float* wrootT = wT + 8192;
  float acc[32];
#pragma unroll
  for (int o = 0; o < 32; ++o) acc[o] = 0.f;
  for (int k = 0; k < 64; ++k) {
    float av = asT[k * 65 + lane];
    float xv = xsT[k * 65 + lane];
    const float* wr = wrelT + k * 128 + o0;
    const float* wo = wrootT + k * 128 + o0;
#pragma unroll
    for (int o = 0; o < 32; ++o) acc[o] += av * wr[o] + xv * wo[o];
  }
  __syncthreads();
#pragma unroll
  for (int o = 0; o < 32; ++o)
    sm[(o0 + o) * 65 + lane] = fmaxf(acc[o] + b1[o0 + o], 0.f);
  __syncthreads();

  for (int i = t; i < 8192; i += 256) {
    int n = i >> 7, o = i & 127;
    int node = base + n;
    if (node < NN) h1[(size_t)node * 128 + o] = sm[o * 65 + n];
  }

  int p0 = __builtin_amdgcn_readfirstlane(wv * 16);
  const float* w2relT = wT + 16384;
  float acc2[16];
#pragma unroll
  for (int o = 0; o < 16; ++o) acc2[o] = 0.f;
  for (int k = 0; k < 128; ++k) {
    float hv = sm[k * 65 + lane];
    const float* w = w2relT + k * 64 + p0;
#pragma unroll
    for (int o = 0; o < 16; ++o) acc2[o] += hv * w[o];
  }
  __syncthreads();
#pragma unroll
  for (int o = 0; o < 16; ++o) sm[(p0 + o) * 65 + lane] = acc2[o];
  __syncthreads();
  for (int i = t; i < 4096; i += 256) {
    int n = i >> 6, o = i & 63;
    int node = base + n;
    if (node < NN) y[(size_t)node * 64 + o] = sm[o * 65 + n];
  }
}

// ---------------- layer 2 + pooling ----------------
__global__ __launch_bounds__(256, 2) void klayer2(
    const float* __restrict__ h1, const float* __restrict__ aggy,
    const float* __restrict__ wT, const float* __restrict__ b2,
    const int* __restrict__ batch, float* __restrict__ pool,
    float* __restrict__ cnt) {
  __shared__ float sm[8320];
  __shared__ float aT[4160];
  __shared__ float pl[4096];
  __shared__ float cl[64];
  int t = threadIdx.x;
  int lane = t & 63;
  int wv = t >> 6;
  int base = blockIdx.x * 64;

  for (int i = t; i < 8192; i += 256) {
    int n = i >> 7, k = i & 127;
    int node = base + n;
    sm[k * 65 + n] = (node < NN) ? h1[(size_t)node * 128 + k] : 0.f;
  }
  for (int i = t; i < 4096; i += 256) {
    int n = i >> 6, o = i & 63;
    int node = base + n;
    aT[o * 65 + n] = (node < NN) ? aggy[(size_t)node * 64 + o] : 0.f;
    pl[i] = 0.f;
  }
  if (t < 64) cl[t] = 0.f;
  __syncthreads();

  int p0 = __builtin_amdgcn_readfirstlane(wv * 16);
  const float* w2rootT = wT + 24576;
  float acc[16];
#pragma unroll
  for (int o = 0; o < 16; ++o) acc[o] = 0.f;
  for (int k = 0; k < 128; ++k) {
    float hv = sm[k * 65 + lane];
    const float* w = w2rootT + k * 64 + p0;
#pragma unroll
    for (int o = 0; o < 16; ++o) acc[o] += hv * w[o];
  }

  int node = base + lane;
  if (node < NN) {
    int g = batch[node];
#pragma unroll
    for (int o = 0; o < 16; ++o) {
      float v = fmaxf(acc[o] + aT[(p0 + o) * 65 + lane] + b2[p0 + o], 0.f);
      atomicAdd(&pl[g * 64 + p0 + o], v);
    }
    if (wv == 0) atomicAdd(&cl[g], 1.f);
  }
  __syncthreads();

  for (int i = t; i < 4096; i += 256) {
    float v = pl[i];
    if (v != 0.f) atomicAdd(&pool[i], v);
  }
  if (t < 64) {
    float c = cl[t];
    if (c != 0.f) atomicAdd(&cnt[t], c);
  }
}

// ---------------- pooled MLPs ----------------
__global__ void kfinal(const float* __restrict__ pool, const float* __restrict__ cnt,
                       const float* __restrict__ es_w1, const float* __restrict__ es_b1,
                       const float* __restrict__ es_w2, const float* __restrict__ es_b2,
                       const float* __restrict__ es_w3, const float* __restrict__ es_b3,
                       const float* __restrict__ d_w1, const float* __restrict__ d_b1,
                       const float* __restrict__ d_w2, const float* __restrict__ d_b2,
                       const float* __restrict__ d_w3, const float* __restrict__ d_b3,
                       float* __restrict__ out) {
  int g = threadIdx.x;
  if (g >= 64) return;
  float c = fmaxf(cnt[g], 1.f);
  float h3[64];
#pragma unroll
  for (int o = 0; o < 64; ++o) {
    h3[o] = pool[g * 64 + o] / c;
    out[g * 64 + o] = h3[o];
  }
  float z1[8];
#pragma unroll
  for (int j = 0; j < 8; ++j) {
    float a = es_b1[j];
#pragma unroll
    for (int k = 0; k < 64; ++k) a += es_w1[j * 64 + k] * h3[k];
    z1[j] = fmaxf(a, 0.f);
  }
  float z2[4];
#pragma unroll
  for (int j = 0; j < 4; ++j) {
    float a = es_b2[j];
#pragma unroll
    for (int k = 0; k < 8; ++k) a += es_w2[j * 8 + k] * z1[k];
    z2[j] = fmaxf(a, 0.f);
  }
  float z = es_b3[0];
#pragma unroll
  for (int k = 0; k < 4; ++k) z += es_w3[k] * z2[k];
  float t1[4];
#pragma unroll
  for (int j = 0; j < 4; ++j) t1[j] = fmaxf(d_w1[j] * z + d_b1[j], 0.f);
  float t2[8];
#pragma unroll
  for (int j = 0; j < 8; ++j) {
    float a = d_b2[j];
#pragma unroll
    for (int k = 0; k < 4; ++k) a += d_w2[j * 4 + k] * t1[k];
    t2[j] = fmaxf(a, 0.f);
  }
#pragma unroll
  for (int o = 0; o < 64; ++o) {
    float a = d_b3[o];
#pragma unroll
    for (int k = 0; k < 8; ++k) a += d_w3[o * 8 + k] * t2[k];
    out[4096 + g * 64 + o] = a;
  }
}

extern "C" void kernel_launch(void* const* d_in, const int* in_sizes, int n_in,
                              void* d_out, int out_size, void* d_ws, size_t ws_size,
                              hipStream_t stream) {
  const float* x = (const float*)d_in[0];
  const int* ei = (const int*)d_in[1];
  const int* srcI = ei;
  const int* dstI = ei + EE;
  const int* batch = (const int*)d_in[2];
  const float* w1_rel = (const float*)d_in[3];
  const float* b1_rel = (const float*)d_in[4];
  const float* w1_root = (const float*)d_in[5];
  const float* w2_rel = (const float*)d_in[6];
  const float* b2_rel = (const float*)d_in[7];
  const float* w2_root = (const float*)d_in[8];
  const float* es_w1 = (const float*)d_in[9];
  const float* es_b1 = (const float*)d_in[10];
  const float* es_w2 = (const float*)d_in[11];
  const float* es_b2 = (const float*)d_in[12];
  const float* es_w3 = (const float*)d_in[13];
  const float* es_b3 = (const float*)d_in[14];
  const float* d_w1 = (const float*)d_in[15];
  const float* d_b1 = (const float*)d_in[16];
  const float* d_w2 = (const float*)d_in[17];
  const float* d_b2 = (const float*)d_in[18];
  const float* d_w3 = (const float*)d_in[19];
  const float* d_b3 = (const float*)d_in[20];

  float* ws = (float*)d_ws;
  float* agg = ws;                          // N*64 (agg1, reused as agg2y)
  float* h1 = ws + (size_t)NN * 64;         // N*128
  float* y = ws + (size_t)NN * 192;         // N*64
  float* pool = ws + (size_t)NN * 256;      // 4096
  float* cntp = pool + 4096;                // 64
  float* wT = cntp + 64;                    // 32768
  int* counts = (int*)(wT + 32768);         // NN
  int* starts = counts + NN;                // NN+1
  int* cursor = starts + NN + 1;            // NN
  int* bsum = cursor + NN;                  // SCAN_NB
  int* boff = bsum + SCAN_NB;               // SCAN_NB
  int* esrc = boff + SCAN_NB;               // EE
  float* out = (float*)d_out;

  hipMemsetAsync(pool, 0, (4096 + 64) * 4, stream);
  hipMemsetAsync(counts, 0, (size_t)NN * 4, stream);
  kprep<<<64, 256, 0, stream>>>(w1_rel, w1_root, w2_rel, w2_root, wT);
  kcount<<<(EE + 255) / 256, 256, 0, stream>>>(dstI, counts);
  kscanA<<<SCAN_NB, 256, 0, stream>>>(counts, bsum);
  kscanB<<<1, 512, 0, stream>>>(bsum, boff);
  kscanC<<<SCAN_NB, 256, 0, stream>>>(counts, boff, starts, cursor);
  kfill<<<(EE + 255) / 256, 256, 0, stream>>>(srcI, dstI, cursor, esrc);
  kgather<<<(NN * 64 + 255) / 256, 256, 0, stream>>>(x, starts, esrc, agg);
  klayer1<<<(NN + 63) / 64, 256, 0, stream>>>(x, agg, wT, b1_rel, h1, y);
  kgather<<<(NN * 64 + 255) / 256, 256, 0, stream>>>(y, starts, esrc, agg);
  klayer2<<<(NN + 63) / 64, 256, 0, stream>>>(h1, agg, wT, b2_rel, batch, pool, cntp);
  kfinal<<<1, 64, 0, stream>>>(pool, cntp, es_w1, es_b1, es_w2, es_b2, es_w3, es_b3,
                               d_w1, d_b1, d_w2, d_b2, d_w3, d_b3, out);
}

// Round 4
// 358.766 us; speedup vs baseline: 6.7019x; 1.4795x over previous
//
#include <hip/hip_runtime.h>
#include <stdint.h>

#define NN 100000
#define EE 1250000
#define SCAN_NB ((NN + 255) / 256)  // 391

typedef __attribute__((ext_vector_type(8))) short short8;
typedef __attribute__((ext_vector_type(4))) float f32x4;

__device__ inline ushort f2bf(float f) {
  union { float f; uint32_t u; } v; v.f = f;
  uint32_t r = v.u + 0x7FFF + ((v.u >> 16) & 1);
  return (ushort)(r >> 16);
}
__device__ inline float bf2f(ushort h) {
  union { uint32_t u; float f; } v; v.u = ((uint32_t)h) << 16;
  return v.f;
}

// ---------------- weight fragment prep (bf16, MFMA B-operand order) ----------------
// B-frag for out-tile t, kstep s: lane l elem j <- w[t*16+(l&15)][s*32+(l>>4)*8+j]
// WF layout (ushort): [0,8192) w1rel (8t x 2s), [8192,16384) w1root,
//                     [16384,24576) w2rel (4t x 4s), [24576,32768) w2root
__global__ __launch_bounds__(256) void kprepfrag(const float* __restrict__ w1_rel,
                                                 const float* __restrict__ w1_root,
                                                 const float* __restrict__ w2_rel,
                                                 const float* __restrict__ w2_root,
                                                 ushort* __restrict__ WF) {
  int idx = blockIdx.x * 256 + threadIdx.x;
  if (idx >= 8192) return;
  int j = idx & 7, l = (idx >> 3) & 63, ts = idx >> 9;  // ts in 0..15
  // layer-1 mats: K=64, ksteps=2, tiles=8 -> ts = t*2+s
  {
    int s = ts & 1, t = ts >> 1;
    int o = t * 16 + (l & 15), k = s * 32 + (l >> 4) * 8 + j;
    WF[idx] = f2bf(w1_rel[o * 64 + k]);
    WF[8192 + idx] = f2bf(w1_root[o * 64 + k]);
  }
  // layer-2 mats: K=128, ksteps=4, tiles=4 -> ts = t*4+s
  {
    int s = ts & 3, t = ts >> 2;
    int o = t * 16 + (l & 15), k = s * 32 + (l >> 4) * 8 + j;
    WF[16384 + idx] = f2bf(w2_rel[o * 128 + k]);
    WF[24576 + idx] = f2bf(w2_root[o * 128 + k]);
  }
}

// ---------------- CSR build: count / 3-phase scan / fill ----------------
__global__ __launch_bounds__(256) void kcount(const int* __restrict__ dstI,
                                              int* __restrict__ counts) {
  int e = blockIdx.x * 256 + threadIdx.x;
  if (e < EE) atomicAdd(&counts[dstI[e]], 1);
}

__global__ __launch_bounds__(256) void kscanA(const int* __restrict__ counts,
                                              int* __restrict__ bsum) {
  __shared__ int red[256];
  int t = threadIdx.x;
  int i = blockIdx.x * 256 + t;
  red[t] = (i < NN) ? counts[i] : 0;
  __syncthreads();
  for (int s = 128; s > 0; s >>= 1) {
    if (t < s) red[t] += red[t + s];
    __syncthreads();
  }
  if (t == 0) bsum[blockIdx.x] = red[0];
}

__global__ __launch_bounds__(512) void kscanB(const int* __restrict__ bsum,
                                              int* __restrict__ boff) {
  __shared__ int sm[512];
  int t = threadIdx.x;
  int v = (t < SCAN_NB) ? bsum[t] : 0;
  sm[t] = v;
  __syncthreads();
  for (int d = 1; d < 512; d <<= 1) {
    int u = (t >= d) ? sm[t - d] : 0;
    __syncthreads();
    sm[t] += u;
    __syncthreads();
  }
  if (t < SCAN_NB) boff[t] = sm[t] - v;
}

__global__ __launch_bounds__(256) void kscanC(const int* __restrict__ counts,
                                              const int* __restrict__ boff,
                                              int* __restrict__ starts,
                                              int* __restrict__ cursor) {
  __shared__ int sm[256];
  int t = threadIdx.x;
  int i = blockIdx.x * 256 + t;
  int v = (i < NN) ? counts[i] : 0;
  sm[t] = v;
  __syncthreads();
  for (int d = 1; d < 256; d <<= 1) {
    int u = (t >= d) ? sm[t - d] : 0;
    __syncthreads();
    sm[t] += u;
    __syncthreads();
  }
  int ex = sm[t] - v + boff[blockIdx.x];
  if (i < NN) {
    starts[i] = ex;
    cursor[i] = ex;
  }
  if (i == NN - 1) starts[NN] = EE;
}

__global__ __launch_bounds__(256) void kfill(const int* __restrict__ srcI,
                                             const int* __restrict__ dstI,
                                             int* __restrict__ cursor,
                                             int* __restrict__ esrc) {
  int e = blockIdx.x * 256 + threadIdx.x;
  if (e >= EE) return;
  int d = dstI[e];
  int pos = atomicAdd(&cursor[d], 1);
  esrc[pos] = srcI[e];
}

// ---------------- gather 1: agg1 = sum x[src] (f32 rows -> bf16 out) ----------------
__global__ __launch_bounds__(256) void kgather1(const float* __restrict__ feat,
                                                const int* __restrict__ starts,
                                                const int* __restrict__ esrc,
                                                ushort* __restrict__ outb) {
  int w = (blockIdx.x * 256 + threadIdx.x) >> 6;
  int lane = threadIdx.x & 63;
  if (w >= NN) return;
  int b = starts[w], e = starts[w + 1];
  float acc = 0.f;
  int i = b;
  for (; i + 4 <= e; i += 4) {
    int s0 = __builtin_amdgcn_readfirstlane(esrc[i]);
    int s1 = __builtin_amdgcn_readfirstlane(esrc[i + 1]);
    int s2 = __builtin_amdgcn_readfirstlane(esrc[i + 2]);
    int s3 = __builtin_amdgcn_readfirstlane(esrc[i + 3]);
    float v0 = feat[(size_t)s0 * 64 + lane];
    float v1 = feat[(size_t)s1 * 64 + lane];
    float v2 = feat[(size_t)s2 * 64 + lane];
    float v3 = feat[(size_t)s3 * 64 + lane];
    acc += (v0 + v1) + (v2 + v3);
  }
  for (; i < e; ++i) {
    int s = __builtin_amdgcn_readfirstlane(esrc[i]);
    acc += feat[(size_t)s * 64 + lane];
  }
  outb[(size_t)w * 64 + lane] = f2bf(acc);
}

// ---------------- gather 2: agg2y = sum y[src] (bf16 rows -> bf16 out) ----------------
__global__ __launch_bounds__(256) void kgather2(const ushort* __restrict__ featb,
                                                const int* __restrict__ starts,
                                                const int* __restrict__ esrc,
                                                ushort* __restrict__ outb) {
  int w = (blockIdx.x * 256 + threadIdx.x) >> 6;
  int lane = threadIdx.x & 63;
  if (w >= NN) return;
  int b = starts[w], e = starts[w + 1];
  float acc = 0.f;
  int i = b;
  for (; i + 4 <= e; i += 4) {
    int s0 = __builtin_amdgcn_readfirstlane(esrc[i]);
    int s1 = __builtin_amdgcn_readfirstlane(esrc[i + 1]);
    int s2 = __builtin_amdgcn_readfirstlane(esrc[i + 2]);
    int s3 = __builtin_amdgcn_readfirstlane(esrc[i + 3]);
    float v0 = bf2f(featb[(size_t)s0 * 64 + lane]);
    float v1 = bf2f(featb[(size_t)s1 * 64 + lane]);
    float v2 = bf2f(featb[(size_t)s2 * 64 + lane]);
    float v3 = bf2f(featb[(size_t)s3 * 64 + lane]);
    acc += (v0 + v1) + (v2 + v3);
  }
  for (; i < e; ++i) {
    int s = __builtin_amdgcn_readfirstlane(esrc[i]);
    acc += bf2f(featb[(size_t)s * 64 + lane]);
  }
  outb[(size_t)w * 64 + lane] = f2bf(acc);
}

// ---------------- fused MFMA: h1 = relu(agg1@w1rel^T + x@w1root^T + b1);
//                  y = h1@w2rel^T (bf16); r2 = h1@w2root^T (f32) ----------------
// 64 nodes/block, 4 waves; wave wv owns 16-node M-tile. h1 lives only in
// wave-private LDS (XOR-swizzled bf16 [16][128] tile).
__global__ __launch_bounds__(256) void kfused(const float* __restrict__ x,
                                              const ushort* __restrict__ aggb,
                                              const ushort* __restrict__ WF,
                                              const float* __restrict__ b1,
                                              ushort* __restrict__ y,
                                              float* __restrict__ r2) {
  __shared__ __align__(16) char hT[16384];  // 4 waves x (16 nodes x 128 bf16)
  int t = threadIdx.x, l = t & 63, wv = t >> 6;
  int n0 = blockIdx.x * 64 + wv * 16;
  int row = l & 15;   // A-frag row / D col
  int kg = l >> 4;    // A-frag k-group / D row-group
  int nr = n0 + row; if (nr > NN - 1) nr = NN - 1;  // clamp loads

  // A-fragments: agg (bf16 direct) and x (f32 -> cvt)
  short8 aA[2], aX[2];
  {
    const ushort* ap = aggb + (size_t)nr * 64 + kg * 8;
    aA[0] = *(const short8*)(ap);
    aA[1] = *(const short8*)(ap + 32);
    const float* xp = x + (size_t)nr * 64 + kg * 8;
#pragma unroll
    for (int s = 0; s < 2; ++s) {
      union { short8 v; ushort u[8]; } tmp;
#pragma unroll
      for (int j = 0; j < 8; ++j) tmp.u[j] = f2bf(xp[s * 32 + j]);
      aX[s] = tmp.v;
    }
  }

  const ushort* wf1rel = WF;
  const ushort* wf1root = WF + 8192;
  char* basep = hT + wv * 4096;

  // GEMM1: 8 out-tiles of 16 -> h1 tile in LDS
#pragma unroll
  for (int tt = 0; tt < 8; ++tt) {
    f32x4 acc = {0.f, 0.f, 0.f, 0.f};
#pragma unroll
    for (int s = 0; s < 2; ++s) {
      short8 br = *(const short8*)(wf1rel + ((size_t)(tt * 2 + s) * 64 + l) * 8);
      acc = __builtin_amdgcn_mfma_f32_16x16x32_bf16(aA[s], br, acc, 0, 0, 0);
      short8 bo = *(const short8*)(wf1root + ((size_t)(tt * 2 + s) * 64 + l) * 8);
      acc = __builtin_amdgcn_mfma_f32_16x16x32_bf16(aX[s], bo, acc, 0, 0, 0);
    }
    float bias = b1[tt * 16 + row];
#pragma unroll
    for (int r = 0; r < 4; ++r) {
      float hv = fmaxf(acc[r] + bias, 0.f);
      int nl = kg * 4 + r;
      int off = nl * 256 + (tt * 16 + row) * 2;
      off ^= (nl & 7) << 4;  // G4 XOR swizzle
      *(ushort*)(basep + off) = f2bf(hv);
    }
  }
  __syncthreads();

  // re-fragment h1 as A-operand (K=128 -> 4 ksteps)
  short8 aH[4];
#pragma unroll
  for (int s = 0; s < 4; ++s) {
    int off = row * 256 + s * 64 + kg * 16;
    off ^= (row & 7) << 4;
    aH[s] = *(const short8*)(basep + off);
  }

  const ushort* wf2rel = WF + 16384;
  const ushort* wf2root = WF + 24576;
#pragma unroll
  for (int tt = 0; tt < 4; ++tt) {
    f32x4 accY = {0.f, 0.f, 0.f, 0.f};
    f32x4 accR = {0.f, 0.f, 0.f, 0.f};
#pragma unroll
    for (int s = 0; s < 4; ++s) {
      short8 br = *(const short8*)(wf2rel + ((size_t)(tt * 4 + s) * 64 + l) * 8);
      accY = __builtin_amdgcn_mfma_f32_16x16x32_bf16(aH[s], br, accY, 0, 0, 0);
      short8 bo = *(const short8*)(wf2root + ((size_t)(tt * 4 + s) * 64 + l) * 8);
      accR = __builtin_amdgcn_mfma_f32_16x16x32_bf16(aH[s], bo, accR, 0, 0, 0);
    }
#pragma unroll
    for (int r = 0; r < 4; ++r) {
      int nd = n0 + kg * 4 + r;
      if (nd < NN) {
        y[(size_t)nd * 64 + tt * 16 + row] = f2bf(accY[r]);
        r2[(size_t)nd * 64 + tt * 16 + row] = accR[r];
      }
    }
  }
}

// ---------------- h2 = relu(aggy + r2 + b2); run-length pool by sorted batch ----------------
__global__ __launch_bounds__(256) void kpool(const ushort* __restrict__ aggy,
                                             const float* __restrict__ r2,
                                             const float* __restrict__ b2v,
                                             const int* __restrict__ batch,
                                             float* __restrict__ pool) {
  int t = threadIdx.x, l = t & 63, wv = t >> 6;
  int nstart = blockIdx.x * 256 + wv * 64;
  float bias = b2v[l];
  float acc = 0.f;
  int curg = -1;
  for (int i = 0; i < 64; ++i) {
    int n = nstart + i;
    if (n >= NN) break;
    int g = __builtin_amdgcn_readfirstlane(batch[n]);
    if (g != curg) {
      if (curg >= 0) atomicAdd(&pool[curg * 64 + l], acc);
      curg = g;
      acc = 0.f;
    }
    float v = bf2f(aggy[(size_t)n * 64 + l]) + r2[(size_t)n * 64 + l] + bias;
    acc += fmaxf(v, 0.f);
  }
  if (curg >= 0) atomicAdd(&pool[curg * 64 + l], acc);
}

// ---------------- pooled MLPs (+ per-graph counts via binary search) ----------------
__global__ void kfinal(const float* __restrict__ pool, const int* __restrict__ batch,
                       const float* __restrict__ es_w1, const float* __restrict__ es_b1,
                       const float* __restrict__ es_w2, const float* __restrict__ es_b2,
                       const float* __restrict__ es_w3, const float* __restrict__ es_b3,
                       const float* __restrict__ d_w1, const float* __restrict__ d_b1,
                       const float* __restrict__ d_w2, const float* __restrict__ d_b2,
                       const float* __restrict__ d_w3, const float* __restrict__ d_b3,
                       float* __restrict__ out) {
  int g = threadIdx.x;
  if (g >= 64) return;
  // lower_bound(batch, g) and lower_bound(batch, g+1)
  int lo0 = 0, hi0 = NN;
  while (lo0 < hi0) { int m = (lo0 + hi0) >> 1; if (batch[m] < g) lo0 = m + 1; else hi0 = m; }
  int lo1 = lo0, hi1 = NN;
  while (lo1 < hi1) { int m = (lo1 + hi1) >> 1; if (batch[m] < g + 1) lo1 = m + 1; else hi1 = m; }
  float c = fmaxf((float)(lo1 - lo0), 1.f);
  float h3[64];
#pragma unroll
  for (int o = 0; o < 64; ++o) {
    h3[o] = pool[g * 64 + o] / c;
    out[g * 64 + o] = h3[o];
  }
  float z1[8];
#pragma unroll
  for (int j = 0; j < 8; ++j) {
    float a = es_b1[j];
#pragma unroll
    for (int k = 0; k < 64; ++k) a += es_w1[j * 64 + k] * h3[k];
    z1[j] = fmaxf(a, 0.f);
  }
  float z2[4];
#pragma unroll
  for (int j = 0; j < 4; ++j) {
    float a = es_b2[j];
#pragma unroll
    for (int k = 0; k < 8; ++k) a += es_w2[j * 8 + k] * z1[k];
    z2[j] = fmaxf(a, 0.f);
  }
  float z = es_b3[0];
#pragma unroll
  for (int k = 0; k < 4; ++k) z += es_w3[k] * z2[k];
  float t1[4];
#pragma unroll
  for (int j = 0; j < 4; ++j) t1[j] = fmaxf(d_w1[j] * z + d_b1[j], 0.f);
  float t2[8];
#pragma unroll
  for (int j = 0; j < 8; ++j) {
    float a = d_b2[j];
#pragma unroll
    for (int k = 0; k < 4; ++k) a += d_w2[j * 4 + k] * t1[k];
    t2[j] = fmaxf(a, 0.f);
  }
#pragma unroll
  for (int o = 0; o < 64; ++o) {
    float a = d_b3[o];
#pragma unroll
    for (int k = 0; k < 8; ++k) a += d_w3[o * 8 + k] * t2[k];
    out[4096 + g * 64 + o] = a;
  }
}

extern "C" void kernel_launch(void* const* d_in, const int* in_sizes, int n_in,
                              void* d_out, int out_size, void* d_ws, size_t ws_size,
                              hipStream_t stream) {
  const float* x = (const float*)d_in[0];
  const int* ei = (const int*)d_in[1];
  const int* srcI = ei;
  const int* dstI = ei + EE;
  const int* batch = (const int*)d_in[2];
  const float* w1_rel = (const float*)d_in[3];
  const float* b1_rel = (const float*)d_in[4];
  const float* w1_root = (const float*)d_in[5];
  const float* w2_rel = (const float*)d_in[6];
  const float* b2_rel = (const float*)d_in[7];
  const float* w2_root = (const float*)d_in[8];
  const float* es_w1 = (const float*)d_in[9];
  const float* es_b1 = (const float*)d_in[10];
  const float* es_w2 = (const float*)d_in[11];
  const float* es_b2 = (const float*)d_in[12];
  const float* es_w3 = (const float*)d_in[13];
  const float* es_b3 = (const float*)d_in[14];
  const float* d_w1 = (const float*)d_in[15];
  const float* d_b1 = (const float*)d_in[16];
  const float* d_w2 = (const float*)d_in[17];
  const float* d_b2 = (const float*)d_in[18];
  const float* d_w3 = (const float*)d_in[19];
  const float* d_b3 = (const float*)d_in[20];

  ushort* aggb = (ushort*)d_ws;                 // NN*64 bf16
  ushort* yb = aggb + (size_t)NN * 64;          // NN*64 bf16
  ushort* aggy = yb + (size_t)NN * 64;          // NN*64 bf16
  float* r2 = (float*)(aggy + (size_t)NN * 64); // NN*64 f32
  float* pool = r2 + (size_t)NN * 64;           // 4096
  ushort* WF = (ushort*)(pool + 4096);          // 32768 bf16
  int* counts = (int*)(WF + 32768);             // NN
  int* starts = counts + NN;                    // NN+1
  int* cursor = starts + NN + 1;                // NN
  int* bsum = cursor + NN;                      // SCAN_NB
  int* boff = bsum + SCAN_NB;                   // SCAN_NB
  int* esrc = boff + SCAN_NB;                   // EE
  float* out = (float*)d_out;

  hipMemsetAsync(pool, 0, 4096 * 4, stream);
  hipMemsetAsync(counts, 0, (size_t)NN * 4, stream);
  kprepfrag<<<32, 256, 0, stream>>>(w1_rel, w1_root, w2_rel, w2_root, WF);
  kcount<<<(EE + 255) / 256, 256, 0, stream>>>(dstI, counts);
  kscanA<<<SCAN_NB, 256, 0, stream>>>(counts, bsum);
  kscanB<<<1, 512, 0, stream>>>(bsum, boff);
  kscanC<<<SCAN_NB, 256, 0, stream>>>(counts, boff, starts, cursor);
  kfill<<<(EE + 255) / 256, 256, 0, stream>>>(srcI, dstI, cursor, esrc);
  kgather1<<<(NN * 64 + 255) / 256, 256, 0, stream>>>(x, starts, esrc, aggb);
  kfused<<<(NN + 63) / 64, 256, 0, stream>>>(x, aggb, WF, b1_rel, yb, r2);
  kgather2<<<(NN * 64 + 255) / 256, 256, 0, stream>>>(yb, starts, esrc, aggy);
  kpool<<<(NN + 255) / 256, 256, 0, stream>>>(aggy, r2, b2_rel, batch, pool);
  kfinal<<<1, 64, 0, stream>>>(pool, batch, es_w1, es_b1, es_w2, es_b2, es_w3, es_b3,
                               d_w1, d_b1, d_w2, d_b2, d_w3, d_b3, out);
}

// Round 5
// 293.080 us; speedup vs baseline: 8.2040x; 1.2241x over previous
//
#include <hip/hip_runtime.h>
#include <stdint.h>

#define NN 100000
#define EE 1250000
#define NBUCK 196          // ceil(NN/512)
#define CHUNK 8192
#define NCHUNK ((EE + CHUNK - 1) / CHUNK)  // 153

typedef __attribute__((ext_vector_type(8))) short short8;
typedef __attribute__((ext_vector_type(4))) float f32x4;

__device__ inline ushort f2bf(float f) {
  union { float f; uint32_t u; } v; v.f = f;
  uint32_t r = v.u + 0x7FFF + ((v.u >> 16) & 1);
  return (ushort)(r >> 16);
}
__device__ inline float bf2f(ushort h) {
  union { uint32_t u; float f; } v; v.u = ((uint32_t)h) << 16;
  return v.f;
}

// ---------------- weight fragment prep (bf16, MFMA B-operand order) ----------------
__global__ __launch_bounds__(256) void kprepfrag(const float* __restrict__ w1_rel,
                                                 const float* __restrict__ w1_root,
                                                 const float* __restrict__ w2_rel,
                                                 const float* __restrict__ w2_root,
                                                 ushort* __restrict__ WF) {
  int idx = blockIdx.x * 256 + threadIdx.x;
  if (idx >= 8192) return;
  int j = idx & 7, l = (idx >> 3) & 63, ts = idx >> 9;
  {
    int s = ts & 1, t = ts >> 1;
    int o = t * 16 + (l & 15), k = s * 32 + (l >> 4) * 8 + j;
    WF[idx] = f2bf(w1_rel[o * 64 + k]);
    WF[8192 + idx] = f2bf(w1_root[o * 64 + k]);
  }
  {
    int s = ts & 3, t = ts >> 2;
    int o = t * 16 + (l & 15), k = s * 32 + (l >> 4) * 8 + j;
    WF[16384 + idx] = f2bf(w2_rel[o * 128 + k]);
    WF[24576 + idx] = f2bf(w2_root[o * 128 + k]);
  }
}

// ---------------- x (f32) -> xb (bf16) ----------------
__global__ __launch_bounds__(256) void kxcvt(const float* __restrict__ x,
                                             ushort* __restrict__ xb) {
  int i = (blockIdx.x * 256 + threadIdx.x) * 4;
  if (i >= NN * 64) return;
  float4 v = *reinterpret_cast<const float4*>(x + i);
  ushort o[4] = {f2bf(v.x), f2bf(v.y), f2bf(v.z), f2bf(v.w)};
  *reinterpret_cast<uint2*>(xb + i) = *reinterpret_cast<uint2*>(o);
}

// ---------------- coarse-bucket histogram (bucket = dst >> 9) ----------------
__global__ __launch_bounds__(256) void khist(const int* __restrict__ dstI,
                                             int* __restrict__ bucketCount) {
  __shared__ int h[NBUCK];
  int t = threadIdx.x;
  for (int b = t; b < NBUCK; b += 256) h[b] = 0;
  __syncthreads();
  for (int e = blockIdx.x * 256 + t; e < EE; e += 256 * 256)
    atomicAdd(&h[dstI[e] >> 9], 1);
  __syncthreads();
  for (int b = t; b < NBUCK; b += 256)
    if (h[b]) atomicAdd(&bucketCount[b], h[b]);
}

// ---------------- scan 196 bucket counts -> starts + cursors ----------------
__global__ __launch_bounds__(256) void kscan196(const int* __restrict__ bucketCount,
                                                int* __restrict__ bucketStart,
                                                int* __restrict__ bucketCursor) {
  __shared__ int ss[256];
  int t = threadIdx.x;
  int v = (t < NBUCK) ? bucketCount[t] : 0;
  ss[t] = v;
  __syncthreads();
  for (int d = 1; d < 256; d <<= 1) {
    int u = (t >= d) ? ss[t - d] : 0;
    __syncthreads();
    ss[t] += u;
    __syncthreads();
  }
  int ex = ss[t] - v;
  if (t < NBUCK) {
    bucketStart[t] = ex;
    bucketCursor[t] = ex;
  }
  if (t == NBUCK - 1) bucketStart[NBUCK] = ss[t];
}

// ---------------- pass A: chunk-local LDS binning into coarse buckets ----------------
// pairsG entry: src | (dstLocal << 17), dstLocal = dst & 511
__global__ __launch_bounds__(256) void kbinA(const int* __restrict__ srcI,
                                             const int* __restrict__ dstI,
                                             int* __restrict__ bucketCursor,
                                             uint32_t* __restrict__ pairsG) {
  __shared__ uint32_t pko[CHUNK];       // 32 KB
  __shared__ int hcnt[NBUCK];
  __shared__ int ss[256];
  __shared__ int ex[NBUCK + 1];
  __shared__ int cur[NBUCK];
  __shared__ int gbase[NBUCK];
  int t = threadIdx.x;
  int cb = blockIdx.x * CHUNK;
  int cc = EE - cb; if (cc > CHUNK) cc = CHUNK;

  for (int b = t; b < NBUCK; b += 256) hcnt[b] = 0;
  __syncthreads();
  for (int i = t; i < cc; i += 256) atomicAdd(&hcnt[dstI[cb + i] >> 9], 1);
  __syncthreads();
  int v = (t < NBUCK) ? hcnt[t] : 0;
  ss[t] = v;
  __syncthreads();
  for (int d = 1; d < 256; d <<= 1) {
    int u = (t >= d) ? ss[t - d] : 0;
    __syncthreads();
    ss[t] += u;
    __syncthreads();
  }
  if (t < NBUCK) {
    ex[t] = ss[t] - v;
    cur[t] = ss[t] - v;
  }
  if (t == NBUCK - 1) ex[NBUCK] = ss[t];
  __syncthreads();
  // scatter into LDS-ordered buffer
  for (int i = t; i < cc; i += 256) {
    int d = dstI[cb + i];
    int s = srcI[cb + i];
    int b = d >> 9;
    int p = atomicAdd(&cur[b], 1);
    pko[p] = (uint32_t)s | ((uint32_t)(d & 511) << 17);
  }
  __syncthreads();
  for (int b = t; b < NBUCK; b += 256) {
    int c = ex[b + 1] - ex[b];
    gbase[b] = c ? atomicAdd(&bucketCursor[b], c) : 0;
  }
  __syncthreads();
  // flush runs (consecutive i within a bucket -> consecutive global)
  for (int i = t; i < cc; i += 256) {
    int lo = 0, hi = NBUCK - 1;
    while (lo < hi) { int m = (lo + hi + 1) >> 1; if (ex[m] <= i) lo = m; else hi = m - 1; }
    pairsG[gbase[lo] + (i - ex[lo])] = pko[i];
  }
}

// ---------------- pass B: per-bucket node-level CSR (starts + esrc) ----------------
__global__ __launch_bounds__(256) void kbinB(const uint32_t* __restrict__ pairsG,
                                             const int* __restrict__ bucketStart,
                                             int* __restrict__ starts,
                                             int* __restrict__ esrc) {
  __shared__ int hist[512];
  __shared__ int ex2[512];
  __shared__ int part[256];
  int t = threadIdx.x;
  int b = blockIdx.x;
  int nbase = b << 9;
  int base = bucketStart[b];
  int ecnt = bucketStart[b + 1] - base;

  hist[t] = 0; hist[t + 256] = 0;
  __syncthreads();
  for (int i = t; i < ecnt; i += 256) atomicAdd(&hist[pairsG[base + i] >> 17], 1);
  __syncthreads();
  int a = hist[2 * t], c = hist[2 * t + 1];
  part[t] = a + c;
  __syncthreads();
  for (int d = 1; d < 256; d <<= 1) {
    int u = (t >= d) ? part[t - d] : 0;
    __syncthreads();
    part[t] += u;
    __syncthreads();
  }
  int pex = part[t] - (a + c);
  ex2[2 * t] = pex;
  ex2[2 * t + 1] = pex + a;
  __syncthreads();
  for (int n = t; n < 512; n += 256) {
    int node = nbase + n;
    if (node < NN) starts[node] = base + ex2[n];
  }
  if (b == NBUCK - 1 && t == 0) starts[NN] = EE;
  // reuse hist as cursor
  for (int n = t; n < 512; n += 256) hist[n] = ex2[n];
  __syncthreads();
  for (int i = t; i < ecnt; i += 256) {
    uint32_t p = pairsG[base + i];
    int dl = p >> 17;
    int s = p & 0x1FFFF;
    int lp = atomicAdd(&hist[dl], 1);
    esrc[base + lp] = s;
  }
}

// ---------------- CSR gather (bf16 rows in, bf16 out, f32 accumulate) ----------------
__global__ __launch_bounds__(256) void kgatherB(const ushort* __restrict__ featb,
                                                const int* __restrict__ starts,
                                                const int* __restrict__ esrc,
                                                ushort* __restrict__ outb) {
  int w = (blockIdx.x * 256 + threadIdx.x) >> 6;
  int lane = threadIdx.x & 63;
  if (w >= NN) return;
  int b = starts[w], e = starts[w + 1];
  float acc = 0.f;
  int i = b;
  for (; i + 4 <= e; i += 4) {
    int s0 = __builtin_amdgcn_readfirstlane(esrc[i]);
    int s1 = __builtin_amdgcn_readfirstlane(esrc[i + 1]);
    int s2 = __builtin_amdgcn_readfirstlane(esrc[i + 2]);
    int s3 = __builtin_amdgcn_readfirstlane(esrc[i + 3]);
    float v0 = bf2f(featb[(size_t)s0 * 64 + lane]);
    float v1 = bf2f(featb[(size_t)s1 * 64 + lane]);
    float v2 = bf2f(featb[(size_t)s2 * 64 + lane]);
    float v3 = bf2f(featb[(size_t)s3 * 64 + lane]);
    acc += (v0 + v1) + (v2 + v3);
  }
  for (; i < e; ++i) {
    int s = __builtin_amdgcn_readfirstlane(esrc[i]);
    acc += bf2f(featb[(size_t)s * 64 + lane]);
  }
  outb[(size_t)w * 64 + lane] = f2bf(acc);
}

// ---------------- fused MFMA: h1 = relu(agg1@w1rel^T + x@w1root^T + b1);
//                  y = h1@w2rel^T (bf16); r2 = h1@w2root^T (f32) ----------------
__global__ __launch_bounds__(256) void kfused(const ushort* __restrict__ xb,
                                              const ushort* __restrict__ aggb,
                                              const ushort* __restrict__ WF,
                                              const float* __restrict__ b1,
                                              ushort* __restrict__ y,
                                              float* __restrict__ r2) {
  __shared__ __align__(16) char hT[16384];
  int t = threadIdx.x, l = t & 63, wv = t >> 6;
  int n0 = blockIdx.x * 64 + wv * 16;
  int row = l & 15;
  int kg = l >> 4;
  int nr = n0 + row; if (nr > NN - 1) nr = NN - 1;

  short8 aA[2], aX[2];
  {
    const ushort* ap = aggb + (size_t)nr * 64 + kg * 8;
    aA[0] = *(const short8*)(ap);
    aA[1] = *(const short8*)(ap + 32);
    const ushort* xp = xb + (size_t)nr * 64 + kg * 8;
    aX[0] = *(const short8*)(xp);
    aX[1] = *(const short8*)(xp + 32);
  }

  const ushort* wf1rel = WF;
  const ushort* wf1root = WF + 8192;
  char* basep = hT + wv * 4096;

#pragma unroll
  for (int tt = 0; tt < 8; ++tt) {
    f32x4 acc = {0.f, 0.f, 0.f, 0.f};
#pragma unroll
    for (int s = 0; s < 2; ++s) {
      short8 br = *(const short8*)(wf1rel + ((size_t)(tt * 2 + s) * 64 + l) * 8);
      acc = __builtin_amdgcn_mfma_f32_16x16x32_bf16(aA[s], br, acc, 0, 0, 0);
      short8 bo = *(const short8*)(wf1root + ((size_t)(tt * 2 + s) * 64 + l) * 8);
      acc = __builtin_amdgcn_mfma_f32_16x16x32_bf16(aX[s], bo, acc, 0, 0, 0);
    }
    float bias = b1[tt * 16 + row];
#pragma unroll
    for (int r = 0; r < 4; ++r) {
      float hv = fmaxf(acc[r] + bias, 0.f);
      int nl = kg * 4 + r;
      int off = nl * 256 + (tt * 16 + row) * 2;
      off ^= (nl & 7) << 4;
      *(ushort*)(basep + off) = f2bf(hv);
    }
  }
  __syncthreads();

  short8 aH[4];
#pragma unroll
  for (int s = 0; s < 4; ++s) {
    int off = row * 256 + s * 64 + kg * 16;
    off ^= (row & 7) << 4;
    aH[s] = *(const short8*)(basep + off);
  }

  const ushort* wf2rel = WF + 16384;
  const ushort* wf2root = WF + 24576;
#pragma unroll
  for (int tt = 0; tt < 4; ++tt) {
    f32x4 accY = {0.f, 0.f, 0.f, 0.f};
    f32x4 accR = {0.f, 0.f, 0.f, 0.f};
#pragma unroll
    for (int s = 0; s < 4; ++s) {
      short8 br = *(const short8*)(wf2rel + ((size_t)(tt * 4 + s) * 64 + l) * 8);
      accY = __builtin_amdgcn_mfma_f32_16x16x32_bf16(aH[s], br, accY, 0, 0, 0);
      short8 bo = *(const short8*)(wf2root + ((size_t)(tt * 4 + s) * 64 + l) * 8);
      accR = __builtin_amdgcn_mfma_f32_16x16x32_bf16(aH[s], bo, accR, 0, 0, 0);
    }
#pragma unroll
    for (int r = 0; r < 4; ++r) {
      int nd = n0 + kg * 4 + r;
      if (nd < NN) {
        y[(size_t)nd * 64 + tt * 16 + row] = f2bf(accY[r]);
        r2[(size_t)nd * 64 + tt * 16 + row] = accR[r];
      }
    }
  }
}

// ---------------- h2 = relu(aggy + r2 + b2); run-length pool ----------------
__global__ __launch_bounds__(256) void kpool(const ushort* __restrict__ aggy,
                                             const float* __restrict__ r2,
                                             const float* __restrict__ b2v,
                                             const int* __restrict__ batch,
                                             float* __restrict__ pool) {
  int t = threadIdx.x, l = t & 63, wv = t >> 6;
  int nstart = blockIdx.x * 256 + wv * 64;
  float bias = b2v[l];
  float acc = 0.f;
  int curg = -1;
  for (int i = 0; i < 64; ++i) {
    int n = nstart + i;
    if (n >= NN) break;
    int g = __builtin_amdgcn_readfirstlane(batch[n]);
    if (g != curg) {
      if (curg >= 0) atomicAdd(&pool[curg * 64 + l], acc);
      curg = g;
      acc = 0.f;
    }
    float v = bf2f(aggy[(size_t)n * 64 + l]) + r2[(size_t)n * 64 + l] + bias;
    acc += fmaxf(v, 0.f);
  }
  if (curg >= 0) atomicAdd(&pool[curg * 64 + l], acc);
}

// ---------------- pooled MLPs ----------------
__global__ void kfinal(const float* __restrict__ pool, const int* __restrict__ batch,
                       const float* __restrict__ es_w1, const float* __restrict__ es_b1,
                       const float* __restrict__ es_w2, const float* __restrict__ es_b2,
                       const float* __restrict__ es_w3, const float* __restrict__ es_b3,
                       const float* __restrict__ d_w1, const float* __restrict__ d_b1,
                       const float* __restrict__ d_w2, const float* __restrict__ d_b2,
                       const float* __restrict__ d_w3, const float* __restrict__ d_b3,
                       float* __restrict__ out) {
  int g = threadIdx.x;
  if (g >= 64) return;
  int lo0 = 0, hi0 = NN;
  while (lo0 < hi0) { int m = (lo0 + hi0) >> 1; if (batch[m] < g) lo0 = m + 1; else hi0 = m; }
  int lo1 = lo0, hi1 = NN;
  while (lo1 < hi1) { int m = (lo1 + hi1) >> 1; if (batch[m] < g + 1) lo1 = m + 1; else hi1 = m; }
  float c = fmaxf((float)(lo1 - lo0), 1.f);
  float h3[64];
#pragma unroll
  for (int o = 0; o < 64; ++o) {
    h3[o] = pool[g * 64 + o] / c;
    out[g * 64 + o] = h3[o];
  }
  float z1[8];
#pragma unroll
  for (int j = 0; j < 8; ++j) {
    float a = es_b1[j];
#pragma unroll
    for (int k = 0; k < 64; ++k) a += es_w1[j * 64 + k] * h3[k];
    z1[j] = fmaxf(a, 0.f);
  }
  float z2[4];
#pragma unroll
  for (int j = 0; j < 4; ++j) {
    float a = es_b2[j];
#pragma unroll
    for (int k = 0; k < 8; ++k) a += es_w2[j * 8 + k] * z1[k];
    z2[j] = fmaxf(a, 0.f);
  }
  float z = es_b3[0];
#pragma unroll
  for (int k = 0; k < 4; ++k) z += es_w3[k] * z2[k];
  float t1[4];
#pragma unroll
  for (int j = 0; j < 4; ++j) t1[j] = fmaxf(d_w1[j] * z + d_b1[j], 0.f);
  float t2[8];
#pragma unroll
  for (int j = 0; j < 8; ++j) {
    float a = d_b2[j];
#pragma unroll
    for (int k = 0; k < 4; ++k) a += d_w2[j * 4 + k] * t1[k];
    t2[j] = fmaxf(a, 0.f);
  }
#pragma unroll
  for (int o = 0; o < 64; ++o) {
    float a = d_b3[o];
#pragma unroll
    for (int k = 0; k < 8; ++k) a += d_w3[o * 8 + k] * t2[k];
    out[4096 + g * 64 + o] = a;
  }
}

extern "C" void kernel_launch(void* const* d_in, const int* in_sizes, int n_in,
                              void* d_out, int out_size, void* d_ws, size_t ws_size,
                              hipStream_t stream) {
  const float* x = (const float*)d_in[0];
  const int* ei = (const int*)d_in[1];
  const int* srcI = ei;
  const int* dstI = ei + EE;
  const int* batch = (const int*)d_in[2];
  const float* w1_rel = (const float*)d_in[3];
  const float* b1_rel = (const float*)d_in[4];
  const float* w1_root = (const float*)d_in[5];
  const float* w2_rel = (const float*)d_in[6];
  const float* b2_rel = (const float*)d_in[7];
  const float* w2_root = (const float*)d_in[8];
  const float* es_w1 = (const float*)d_in[9];
  const float* es_b1 = (const float*)d_in[10];
  const float* es_w2 = (const float*)d_in[11];
  const float* es_b2 = (const float*)d_in[12];
  const float* es_w3 = (const float*)d_in[13];
  const float* es_b3 = (const float*)d_in[14];
  const float* d_w1 = (const float*)d_in[15];
  const float* d_b1 = (const float*)d_in[16];
  const float* d_w2 = (const float*)d_in[17];
  const float* d_b2 = (const float*)d_in[18];
  const float* d_w3 = (const float*)d_in[19];
  const float* d_b3 = (const float*)d_in[20];

  ushort* xb = (ushort*)d_ws;                     // NN*64 bf16
  ushort* aggb = xb + (size_t)NN * 64;            // NN*64 bf16
  ushort* yb = aggb + (size_t)NN * 64;            // NN*64 bf16
  ushort* aggy = yb + (size_t)NN * 64;            // NN*64 bf16
  float* r2 = (float*)(aggy + (size_t)NN * 64);   // NN*64 f32
  float* pool = r2 + (size_t)NN * 64;             // 4096
  ushort* WF = (ushort*)(pool + 4096);            // 32768 bf16
  int* starts = (int*)(WF + 32768);               // NN+1
  int* bucketCount = starts + NN + 1;             // NBUCK
  int* bucketStart = bucketCount + NBUCK;         // NBUCK+1
  int* bucketCursor = bucketStart + NBUCK + 1;    // NBUCK
  uint32_t* pairsG = (uint32_t*)(bucketCursor + NBUCK);  // EE
  int* esrc = (int*)(pairsG + EE);                // EE
  float* out = (float*)d_out;

  hipMemsetAsync(pool, 0, 4096 * 4, stream);
  hipMemsetAsync(bucketCount, 0, NBUCK * 4, stream);
  kprepfrag<<<32, 256, 0, stream>>>(w1_rel, w1_root, w2_rel, w2_root, WF);
  kxcvt<<<(NN * 64 / 4 + 255) / 256, 256, 0, stream>>>(x, xb);
  khist<<<256, 256, 0, stream>>>(dstI, bucketCount);
  kscan196<<<1, 256, 0, stream>>>(bucketCount, bucketStart, bucketCursor);
  kbinA<<<NCHUNK, 256, 0, stream>>>(srcI, dstI, bucketCursor, pairsG);
  kbinB<<<NBUCK, 256, 0, stream>>>(pairsG, bucketStart, starts, esrc);
  kgatherB<<<(NN * 64 + 255) / 256, 256, 0, stream>>>(xb, starts, esrc, aggb);
  kfused<<<(NN + 63) / 64, 256, 0, stream>>>(xb, aggb, WF, b1_rel, yb, r2);
  kgatherB<<<(NN * 64 + 255) / 256, 256, 0, stream>>>(yb, starts, esrc, aggy);
  kpool<<<(NN + 255) / 256, 256, 0, stream>>>(aggy, r2, b2_rel, batch, pool);
  kfinal<<<1, 64, 0, stream>>>(pool, batch, es_w1, es_b1, es_w2, es_b2, es_w3, es_b3,
                               d_w1, d_b1, d_w2, d_b2, d_w3, d_b3, out);
}

// Round 6
// 275.027 us; speedup vs baseline: 8.7425x; 1.0656x over previous
//
#include <hip/hip_runtime.h>
#include <stdint.h>

#define NN 100000
#define EE 1250000
#define NBUCK 196          // ceil(NN/512)
#define CHUNK 8192
#define NCHUNK ((EE + CHUNK - 1) / CHUNK)  // 153

typedef __attribute__((ext_vector_type(8))) short short8;
typedef __attribute__((ext_vector_type(4))) float f32x4;

__device__ inline ushort f2bf(float f) {
  union { float f; uint32_t u; } v; v.f = f;
  uint32_t r = v.u + 0x7FFF + ((v.u >> 16) & 1);
  return (ushort)(r >> 16);
}
__device__ inline float bf2f(ushort h) {
  union { uint32_t u; float f; } v; v.u = ((uint32_t)h) << 16;
  return v.f;
}

// ---------------- weight fragment prep (bf16, MFMA B-operand order) ----------------
__global__ __launch_bounds__(256) void kprepfrag(const float* __restrict__ w1_rel,
                                                 const float* __restrict__ w1_root,
                                                 const float* __restrict__ w2_rel,
                                                 const float* __restrict__ w2_root,
                                                 ushort* __restrict__ WF) {
  int idx = blockIdx.x * 256 + threadIdx.x;
  if (idx >= 8192) return;
  int j = idx & 7, l = (idx >> 3) & 63, ts = idx >> 9;
  {
    int s = ts & 1, t = ts >> 1;
    int o = t * 16 + (l & 15), k = s * 32 + (l >> 4) * 8 + j;
    WF[idx] = f2bf(w1_rel[o * 64 + k]);
    WF[8192 + idx] = f2bf(w1_root[o * 64 + k]);
  }
  {
    int s = ts & 3, t = ts >> 2;
    int o = t * 16 + (l & 15), k = s * 32 + (l >> 4) * 8 + j;
    WF[16384 + idx] = f2bf(w2_rel[o * 128 + k]);
    WF[24576 + idx] = f2bf(w2_root[o * 128 + k]);
  }
}

// ---------------- x (f32) -> xb (bf16) ----------------
__global__ __launch_bounds__(256) void kxcvt(const float* __restrict__ x,
                                             ushort* __restrict__ xb) {
  int i = (blockIdx.x * 256 + threadIdx.x) * 4;
  if (i >= NN * 64) return;
  float4 v = *reinterpret_cast<const float4*>(x + i);
  ushort o[4] = {f2bf(v.x), f2bf(v.y), f2bf(v.z), f2bf(v.w)};
  *reinterpret_cast<uint2*>(xb + i) = *reinterpret_cast<uint2*>(o);
}

// ---------------- coarse-bucket histogram (bucket = dst >> 9) ----------------
__global__ __launch_bounds__(256) void khist(const int* __restrict__ dstI,
                                             int* __restrict__ bucketCount) {
  __shared__ int h[NBUCK];
  int t = threadIdx.x;
  for (int b = t; b < NBUCK; b += 256) h[b] = 0;
  __syncthreads();
  for (int e = blockIdx.x * 256 + t; e < EE; e += 256 * 256)
    atomicAdd(&h[dstI[e] >> 9], 1);
  __syncthreads();
  for (int b = t; b < NBUCK; b += 256)
    if (h[b]) atomicAdd(&bucketCount[b], h[b]);
}

// ---------------- scan 196 bucket counts -> starts + cursors ----------------
__global__ __launch_bounds__(256) void kscan196(const int* __restrict__ bucketCount,
                                                int* __restrict__ bucketStart,
                                                int* __restrict__ bucketCursor) {
  __shared__ int ss[256];
  int t = threadIdx.x;
  int v = (t < NBUCK) ? bucketCount[t] : 0;
  ss[t] = v;
  __syncthreads();
  for (int d = 1; d < 256; d <<= 1) {
    int u = (t >= d) ? ss[t - d] : 0;
    __syncthreads();
    ss[t] += u;
    __syncthreads();
  }
  int ex = ss[t] - v;
  if (t < NBUCK) {
    bucketStart[t] = ex;
    bucketCursor[t] = ex;
  }
  if (t == NBUCK - 1) bucketStart[NBUCK] = ss[t];
}

// ---------------- pass A: chunk-local LDS binning into coarse buckets ----------------
__global__ __launch_bounds__(256) void kbinA(const int* __restrict__ srcI,
                                             const int* __restrict__ dstI,
                                             int* __restrict__ bucketCursor,
                                             uint32_t* __restrict__ pairsG) {
  __shared__ uint32_t pko[CHUNK];       // 32 KB
  __shared__ int hcnt[NBUCK];
  __shared__ int ss[256];
  __shared__ int ex[NBUCK + 1];
  __shared__ int cur[NBUCK];
  __shared__ int gbase[NBUCK];
  int t = threadIdx.x;
  int cb = blockIdx.x * CHUNK;
  int cc = EE - cb; if (cc > CHUNK) cc = CHUNK;

  for (int b = t; b < NBUCK; b += 256) hcnt[b] = 0;
  __syncthreads();
  for (int i = t; i < cc; i += 256) atomicAdd(&hcnt[dstI[cb + i] >> 9], 1);
  __syncthreads();
  int v = (t < NBUCK) ? hcnt[t] : 0;
  ss[t] = v;
  __syncthreads();
  for (int d = 1; d < 256; d <<= 1) {
    int u = (t >= d) ? ss[t - d] : 0;
    __syncthreads();
    ss[t] += u;
    __syncthreads();
  }
  if (t < NBUCK) {
    ex[t] = ss[t] - v;
    cur[t] = ss[t] - v;
  }
  if (t == NBUCK - 1) ex[NBUCK] = ss[t];
  __syncthreads();
  for (int i = t; i < cc; i += 256) {
    int d = dstI[cb + i];
    int s = srcI[cb + i];
    int b = d >> 9;
    int p = atomicAdd(&cur[b], 1);
    pko[p] = (uint32_t)s | ((uint32_t)(d & 511) << 17);
  }
  __syncthreads();
  for (int b = t; b < NBUCK; b += 256) {
    int c = ex[b + 1] - ex[b];
    gbase[b] = c ? atomicAdd(&bucketCursor[b], c) : 0;
  }
  __syncthreads();
  for (int i = t; i < cc; i += 256) {
    int lo = 0, hi = NBUCK - 1;
    while (lo < hi) { int m = (lo + hi + 1) >> 1; if (ex[m] <= i) lo = m; else hi = m - 1; }
    pairsG[gbase[lo] + (i - ex[lo])] = pko[i];
  }
}

// ---------------- pass B: per-bucket node-level CSR (starts + esrc) ----------------
__global__ __launch_bounds__(256) void kbinB(const uint32_t* __restrict__ pairsG,
                                             const int* __restrict__ bucketStart,
                                             int* __restrict__ starts,
                                             int* __restrict__ esrc) {
  __shared__ int hist[512];
  __shared__ int ex2[512];
  __shared__ int part[256];
  int t = threadIdx.x;
  int b = blockIdx.x;
  int nbase = b << 9;
  int base = bucketStart[b];
  int ecnt = bucketStart[b + 1] - base;

  hist[t] = 0; hist[t + 256] = 0;
  __syncthreads();
  for (int i = t; i < ecnt; i += 256) atomicAdd(&hist[pairsG[base + i] >> 17], 1);
  __syncthreads();
  int a = hist[2 * t], c = hist[2 * t + 1];
  part[t] = a + c;
  __syncthreads();
  for (int d = 1; d < 256; d <<= 1) {
    int u = (t >= d) ? part[t - d] : 0;
    __syncthreads();
    part[t] += u;
    __syncthreads();
  }
  int pex = part[t] - (a + c);
  ex2[2 * t] = pex;
  ex2[2 * t + 1] = pex + a;
  __syncthreads();
  for (int n = t; n < 512; n += 256) {
    int node = nbase + n;
    if (node < NN) starts[node] = base + ex2[n];
  }
  if (b == NBUCK - 1 && t == 0) starts[NN] = EE;
  for (int n = t; n < 512; n += 256) hist[n] = ex2[n];
  __syncthreads();
  for (int i = t; i < ecnt; i += 256) {
    uint32_t p = pairsG[base + i];
    int dl = p >> 17;
    int s = p & 0x1FFFF;
    int lp = atomicAdd(&hist[dl], 1);
    esrc[base + lp] = s;
  }
}

// ---------------- paired CSR gather: half-wave = one row (32 lanes x 4B) ----------------
// Each load instruction fetches 2 rows (one per half); 8-edge unroll => 4 in flight.
__global__ __launch_bounds__(256) void kgatherP(const ushort* __restrict__ featb,
                                                const int* __restrict__ starts,
                                                const int* __restrict__ esrc,
                                                ushort* __restrict__ outb) {
  int w = (blockIdx.x * 256 + threadIdx.x) >> 6;  // node
  int l = threadIdx.x & 63;
  if (w >= NN) return;
  int h = l >> 5;        // half id: processes edges b+2k+h
  int c = l & 31;        // channel pair: channels 2c, 2c+1
  int b = starts[w], e = starts[w + 1];
  float ax = 0.f, ay = 0.f;
  int i = b;
  for (; i + 8 <= e; i += 8) {
    int s0 = esrc[i + h];
    int s1 = esrc[i + 2 + h];
    int s2 = esrc[i + 4 + h];
    int s3 = esrc[i + 6 + h];
    uint32_t u0 = *(const uint32_t*)(featb + (size_t)s0 * 64 + 2 * c);
    uint32_t u1 = *(const uint32_t*)(featb + (size_t)s1 * 64 + 2 * c);
    uint32_t u2 = *(const uint32_t*)(featb + (size_t)s2 * 64 + 2 * c);
    uint32_t u3 = *(const uint32_t*)(featb + (size_t)s3 * 64 + 2 * c);
    ax += bf2f((ushort)u0) + bf2f((ushort)u1) + bf2f((ushort)u2) + bf2f((ushort)u3);
    ay += bf2f((ushort)(u0 >> 16)) + bf2f((ushort)(u1 >> 16)) +
          bf2f((ushort)(u2 >> 16)) + bf2f((ushort)(u3 >> 16));
  }
  for (; i + 2 <= e; i += 2) {
    int s = esrc[i + h];
    uint32_t u = *(const uint32_t*)(featb + (size_t)s * 64 + 2 * c);
    ax += bf2f((ushort)u);
    ay += bf2f((ushort)(u >> 16));
  }
  if (i + h < e) {  // odd tail: only half 0
    int s = esrc[i + h];
    uint32_t u = *(const uint32_t*)(featb + (size_t)s * 64 + 2 * c);
    ax += bf2f((ushort)u);
    ay += bf2f((ushort)(u >> 16));
  }
  // cross-half reduce
  ax += __shfl_xor(ax, 32);
  ay += __shfl_xor(ay, 32);
  if (h == 0) {
    uint32_t o = (uint32_t)f2bf(ax) | ((uint32_t)f2bf(ay) << 16);
    *(uint32_t*)(outb + (size_t)w * 64 + 2 * c) = o;
  }
}

// ---------------- fused MFMA: h1 = relu(agg1@w1rel^T + x@w1root^T + b1);
//                  y = h1@w2rel^T (bf16); r2 = h1@w2root^T (bf16) ----------------
__global__ __launch_bounds__(256) void kfused(const ushort* __restrict__ xb,
                                              const ushort* __restrict__ aggb,
                                              const ushort* __restrict__ WF,
                                              const float* __restrict__ b1,
                                              ushort* __restrict__ y,
                                              ushort* __restrict__ r2b) {
  __shared__ __align__(16) char hT[16384];
  int t = threadIdx.x, l = t & 63, wv = t >> 6;
  int n0 = blockIdx.x * 64 + wv * 16;
  int row = l & 15;
  int kg = l >> 4;
  int nr = n0 + row; if (nr > NN - 1) nr = NN - 1;

  short8 aA[2], aX[2];
  {
    const ushort* ap = aggb + (size_t)nr * 64 + kg * 8;
    aA[0] = *(const short8*)(ap);
    aA[1] = *(const short8*)(ap + 32);
    const ushort* xp = xb + (size_t)nr * 64 + kg * 8;
    aX[0] = *(const short8*)(xp);
    aX[1] = *(const short8*)(xp + 32);
  }

  const ushort* wf1rel = WF;
  const ushort* wf1root = WF + 8192;
  char* basep = hT + wv * 4096;

#pragma unroll
  for (int tt = 0; tt < 8; ++tt) {
    f32x4 acc = {0.f, 0.f, 0.f, 0.f};
#pragma unroll
    for (int s = 0; s < 2; ++s) {
      short8 br = *(const short8*)(wf1rel + ((size_t)(tt * 2 + s) * 64 + l) * 8);
      acc = __builtin_amdgcn_mfma_f32_16x16x32_bf16(aA[s], br, acc, 0, 0, 0);
      short8 bo = *(const short8*)(wf1root + ((size_t)(tt * 2 + s) * 64 + l) * 8);
      acc = __builtin_amdgcn_mfma_f32_16x16x32_bf16(aX[s], bo, acc, 0, 0, 0);
    }
    float bias = b1[tt * 16 + row];
#pragma unroll
    for (int r = 0; r < 4; ++r) {
      float hv = fmaxf(acc[r] + bias, 0.f);
      int nl = kg * 4 + r;
      int off = nl * 256 + (tt * 16 + row) * 2;
      off ^= (nl & 7) << 4;
      *(ushort*)(basep + off) = f2bf(hv);
    }
  }
  __syncthreads();

  short8 aH[4];
#pragma unroll
  for (int s = 0; s < 4; ++s) {
    int off = row * 256 + s * 64 + kg * 16;
    off ^= (row & 7) << 4;
    aH[s] = *(const short8*)(basep + off);
  }

  const ushort* wf2rel = WF + 16384;
  const ushort* wf2root = WF + 24576;
#pragma unroll
  for (int tt = 0; tt < 4; ++tt) {
    f32x4 accY = {0.f, 0.f, 0.f, 0.f};
    f32x4 accR = {0.f, 0.f, 0.f, 0.f};
#pragma unroll
    for (int s = 0; s < 4; ++s) {
      short8 br = *(const short8*)(wf2rel + ((size_t)(tt * 4 + s) * 64 + l) * 8);
      accY = __builtin_amdgcn_mfma_f32_16x16x32_bf16(aH[s], br, accY, 0, 0, 0);
      short8 bo = *(const short8*)(wf2root + ((size_t)(tt * 4 + s) * 64 + l) * 8);
      accR = __builtin_amdgcn_mfma_f32_16x16x32_bf16(aH[s], bo, accR, 0, 0, 0);
    }
#pragma unroll
    for (int r = 0; r < 4; ++r) {
      int nd = n0 + kg * 4 + r;
      if (nd < NN) {
        y[(size_t)nd * 64 + tt * 16 + row] = f2bf(accY[r]);
        r2b[(size_t)nd * 64 + tt * 16 + row] = f2bf(accR[r]);
      }
    }
  }
}

// ---------------- h2 = relu(aggy + r2 + b2); run-length pool ----------------
__global__ __launch_bounds__(256) void kpool(const ushort* __restrict__ aggy,
                                             const ushort* __restrict__ r2b,
                                             const float* __restrict__ b2v,
                                             const int* __restrict__ batch,
                                             float* __restrict__ pool) {
  int t = threadIdx.x, l = t & 63, wv = t >> 6;
  int nstart = blockIdx.x * 256 + wv * 64;
  float bias = b2v[l];
  float acc = 0.f;
  int curg = -1;
  for (int i = 0; i < 64; ++i) {
    int n = nstart + i;
    if (n >= NN) break;
    int g = __builtin_amdgcn_readfirstlane(batch[n]);
    if (g != curg) {
      if (curg >= 0) atomicAdd(&pool[curg * 64 + l], acc);
      curg = g;
      acc = 0.f;
    }
    float v = bf2f(aggy[(size_t)n * 64 + l]) + bf2f(r2b[(size_t)n * 64 + l]) + bias;
    acc += fmaxf(v, 0.f);
  }
  if (curg >= 0) atomicAdd(&pool[curg * 64 + l], acc);
}

// ---------------- pooled MLPs ----------------
__global__ void kfinal(const float* __restrict__ pool, const int* __restrict__ batch,
                       const float* __restrict__ es_w1, const float* __restrict__ es_b1,
                       const float* __restrict__ es_w2, const float* __restrict__ es_b2,
                       const float* __restrict__ es_w3, const float* __restrict__ es_b3,
                       const float* __restrict__ d_w1, const float* __restrict__ d_b1,
                       const float* __restrict__ d_w2, const float* __restrict__ d_b2,
                       const float* __restrict__ d_w3, const float* __restrict__ d_b3,
                       float* __restrict__ out) {
  int g = threadIdx.x;
  if (g >= 64) return;
  int lo0 = 0, hi0 = NN;
  while (lo0 < hi0) { int m = (lo0 + hi0) >> 1; if (batch[m] < g) lo0 = m + 1; else hi0 = m; }
  int lo1 = lo0, hi1 = NN;
  while (lo1 < hi1) { int m = (lo1 + hi1) >> 1; if (batch[m] < g + 1) lo1 = m + 1; else hi1 = m; }
  float c = fmaxf((float)(lo1 - lo0), 1.f);
  float h3[64];
#pragma unroll
  for (int o = 0; o < 64; ++o) {
    h3[o] = pool[g * 64 + o] / c;
    out[g * 64 + o] = h3[o];
  }
  float z1[8];
#pragma unroll
  for (int j = 0; j < 8; ++j) {
    float a = es_b1[j];
#pragma unroll
    for (int k = 0; k < 64; ++k) a += es_w1[j * 64 + k] * h3[k];
    z1[j] = fmaxf(a, 0.f);
  }
  float z2[4];
#pragma unroll
  for (int j = 0; j < 4; ++j) {
    float a = es_b2[j];
#pragma unroll
    for (int k = 0; k < 8; ++k) a += es_w2[j * 8 + k] * z1[k];
    z2[j] = fmaxf(a, 0.f);
  }
  float z = es_b3[0];
#pragma unroll
  for (int k = 0; k < 4; ++k) z += es_w3[k] * z2[k];
  float t1[4];
#pragma unroll
  for (int j = 0; j < 4; ++j) t1[j] = fmaxf(d_w1[j] * z + d_b1[j], 0.f);
  float t2[8];
#pragma unroll
  for (int j = 0; j < 8; ++j) {
    float a = d_b2[j];
#pragma unroll
    for (int k = 0; k < 4; ++k) a += d_w2[j * 4 + k] * t1[k];
    t2[j] = fmaxf(a, 0.f);
  }
#pragma unroll
  for (int o = 0; o < 64; ++o) {
    float a = d_b3[o];
#pragma unroll
    for (int k = 0; k < 8; ++k) a += d_w3[o * 8 + k] * t2[k];
    out[4096 + g * 64 + o] = a;
  }
}

extern "C" void kernel_launch(void* const* d_in, const int* in_sizes, int n_in,
                              void* d_out, int out_size, void* d_ws, size_t ws_size,
                              hipStream_t stream) {
  const float* x = (const float*)d_in[0];
  const int* ei = (const int*)d_in[1];
  const int* srcI = ei;
  const int* dstI = ei + EE;
  const int* batch = (const int*)d_in[2];
  const float* w1_rel = (const float*)d_in[3];
  const float* b1_rel = (const float*)d_in[4];
  const float* w1_root = (const float*)d_in[5];
  const float* w2_rel = (const float*)d_in[6];
  const float* b2_rel = (const float*)d_in[7];
  const float* w2_root = (const float*)d_in[8];
  const float* es_w1 = (const float*)d_in[9];
  const float* es_b1 = (const float*)d_in[10];
  const float* es_w2 = (const float*)d_in[11];
  const float* es_b2 = (const float*)d_in[12];
  const float* es_w3 = (const float*)d_in[13];
  const float* es_b3 = (const float*)d_in[14];
  const float* d_w1 = (const float*)d_in[15];
  const float* d_b1 = (const float*)d_in[16];
  const float* d_w2 = (const float*)d_in[17];
  const float* d_b2 = (const float*)d_in[18];
  const float* d_w3 = (const float*)d_in[19];
  const float* d_b3 = (const float*)d_in[20];

  ushort* xb = (ushort*)d_ws;                     // NN*64 bf16
  ushort* aggb = xb + (size_t)NN * 64;            // NN*64 bf16
  ushort* yb = aggb + (size_t)NN * 64;            // NN*64 bf16
  ushort* aggy = yb + (size_t)NN * 64;            // NN*64 bf16
  ushort* r2b = aggy + (size_t)NN * 64;           // NN*64 bf16
  float* pool = (float*)(r2b + (size_t)NN * 64);  // 4096
  ushort* WF = (ushort*)(pool + 4096);            // 32768 bf16
  int* starts = (int*)(WF + 32768);               // NN+1
  int* bucketCount = starts + NN + 1;             // NBUCK
  int* bucketStart = bucketCount + NBUCK;         // NBUCK+1
  int* bucketCursor = bucketStart + NBUCK + 1;    // NBUCK
  uint32_t* pairsG = (uint32_t*)(bucketCursor + NBUCK);  // EE
  int* esrc = (int*)(pairsG + EE);                // EE
  float* out = (float*)d_out;

  hipMemsetAsync(pool, 0, 4096 * 4, stream);
  hipMemsetAsync(bucketCount, 0, NBUCK * 4, stream);
  kprepfrag<<<32, 256, 0, stream>>>(w1_rel, w1_root, w2_rel, w2_root, WF);
  kxcvt<<<(NN * 64 / 4 + 255) / 256, 256, 0, stream>>>(x, xb);
  khist<<<256, 256, 0, stream>>>(dstI, bucketCount);
  kscan196<<<1, 256, 0, stream>>>(bucketCount, bucketStart, bucketCursor);
  kbinA<<<NCHUNK, 256, 0, stream>>>(srcI, dstI, bucketCursor, pairsG);
  kbinB<<<NBUCK, 256, 0, stream>>>(pairsG, bucketStart, starts, esrc);
  kgatherP<<<(NN * 64 + 255) / 256, 256, 0, stream>>>(xb, starts, esrc, aggb);
  kfused<<<(NN + 63) / 64, 256, 0, stream>>>(xb, aggb, WF, b1_rel, yb, r2b);
  kgatherP<<<(NN * 64 + 255) / 256, 256, 0, stream>>>(yb, starts, esrc, aggy);
  kpool<<<(NN + 255) / 256, 256, 0, stream>>>(aggy, r2b, b2_rel, batch, pool);
  kfinal<<<1, 64, 0, stream>>>(pool, batch, es_w1, es_b1, es_w2, es_b2, es_w3, es_b3,
                               d_w1, d_b1, d_w2, d_b2, d_w3, d_b3, out);
}

// Round 7
// 255.801 us; speedup vs baseline: 9.3996x; 1.0752x over previous
//
#include <hip/hip_runtime.h>
#include <stdint.h>

#define NN 100000
#define EE 1250000
#define NBUCK 196          // ceil(NN/512)
#define CHUNK 8192
#define NCHUNK ((EE + CHUNK - 1) / CHUNK)  // 153

typedef __attribute__((ext_vector_type(8))) short short8;
typedef __attribute__((ext_vector_type(4))) float f32x4;

__device__ inline ushort f2bf(float f) {
  union { float f; uint32_t u; } v; v.f = f;
  uint32_t r = v.u + 0x7FFF + ((v.u >> 16) & 1);
  return (ushort)(r >> 16);
}
__device__ inline float bf2f(ushort h) {
  union { uint32_t u; float f; } v; v.u = ((uint32_t)h) << 16;
  return v.f;
}

// ---------------- weight fragment prep (bf16, MFMA B-operand order) ----------------
__global__ __launch_bounds__(256) void kprepfrag(const float* __restrict__ w1_rel,
                                                 const float* __restrict__ w1_root,
                                                 const float* __restrict__ w2_rel,
                                                 const float* __restrict__ w2_root,
                                                 ushort* __restrict__ WF) {
  int idx = blockIdx.x * 256 + threadIdx.x;
  if (idx >= 8192) return;
  int j = idx & 7, l = (idx >> 3) & 63, ts = idx >> 9;
  {
    int s = ts & 1, t = ts >> 1;
    int o = t * 16 + (l & 15), k = s * 32 + (l >> 4) * 8 + j;
    WF[idx] = f2bf(w1_rel[o * 64 + k]);
    WF[8192 + idx] = f2bf(w1_root[o * 64 + k]);
  }
  {
    int s = ts & 3, t = ts >> 2;
    int o = t * 16 + (l & 15), k = s * 32 + (l >> 4) * 8 + j;
    WF[16384 + idx] = f2bf(w2_rel[o * 128 + k]);
    WF[24576 + idx] = f2bf(w2_root[o * 128 + k]);
  }
}

// ---------------- x (f32) -> xb (bf16) ----------------
__global__ __launch_bounds__(256) void kxcvt(const float* __restrict__ x,
                                             ushort* __restrict__ xb) {
  int i = (blockIdx.x * 256 + threadIdx.x) * 4;
  if (i >= NN * 64) return;
  float4 v = *reinterpret_cast<const float4*>(x + i);
  ushort o[4] = {f2bf(v.x), f2bf(v.y), f2bf(v.z), f2bf(v.w)};
  *reinterpret_cast<uint2*>(xb + i) = *reinterpret_cast<uint2*>(o);
}

// ---------------- coarse-bucket histogram (bucket = dst >> 9) ----------------
__global__ __launch_bounds__(256) void khist(const int* __restrict__ dstI,
                                             int* __restrict__ bucketCount) {
  __shared__ int h[NBUCK];
  int t = threadIdx.x;
  for (int b = t; b < NBUCK; b += 256) h[b] = 0;
  __syncthreads();
  for (int e = blockIdx.x * 256 + t; e < EE; e += 256 * 256)
    atomicAdd(&h[dstI[e] >> 9], 1);
  __syncthreads();
  for (int b = t; b < NBUCK; b += 256)
    if (h[b]) atomicAdd(&bucketCount[b], h[b]);
}

// ---------------- scan 196 bucket counts -> starts + cursors ----------------
__global__ __launch_bounds__(256) void kscan196(const int* __restrict__ bucketCount,
                                                int* __restrict__ bucketStart,
                                                int* __restrict__ bucketCursor) {
  __shared__ int ss[256];
  int t = threadIdx.x;
  int v = (t < NBUCK) ? bucketCount[t] : 0;
  ss[t] = v;
  __syncthreads();
  for (int d = 1; d < 256; d <<= 1) {
    int u = (t >= d) ? ss[t - d] : 0;
    __syncthreads();
    ss[t] += u;
    __syncthreads();
  }
  int ex = ss[t] - v;
  if (t < NBUCK) {
    bucketStart[t] = ex;
    bucketCursor[t] = ex;
  }
  if (t == NBUCK - 1) bucketStart[NBUCK] = ss[t];
}

// ---------------- pass A: chunk-local LDS binning into coarse buckets ----------------
__global__ __launch_bounds__(256) void kbinA(const int* __restrict__ srcI,
                                             const int* __restrict__ dstI,
                                             int* __restrict__ bucketCursor,
                                             uint32_t* __restrict__ pairsG) {
  __shared__ uint32_t pko[CHUNK];       // 32 KB
  __shared__ int hcnt[NBUCK];
  __shared__ int ss[256];
  __shared__ int ex[NBUCK + 1];
  __shared__ int cur[NBUCK];
  __shared__ int gbase[NBUCK];
  int t = threadIdx.x;
  int cb = blockIdx.x * CHUNK;
  int cc = EE - cb; if (cc > CHUNK) cc = CHUNK;

  for (int b = t; b < NBUCK; b += 256) hcnt[b] = 0;
  __syncthreads();
  for (int i = t; i < cc; i += 256) atomicAdd(&hcnt[dstI[cb + i] >> 9], 1);
  __syncthreads();
  int v = (t < NBUCK) ? hcnt[t] : 0;
  ss[t] = v;
  __syncthreads();
  for (int d = 1; d < 256; d <<= 1) {
    int u = (t >= d) ? ss[t - d] : 0;
    __syncthreads();
    ss[t] += u;
    __syncthreads();
  }
  if (t < NBUCK) {
    ex[t] = ss[t] - v;
    cur[t] = ss[t] - v;
  }
  if (t == NBUCK - 1) ex[NBUCK] = ss[t];
  __syncthreads();
  for (int i = t; i < cc; i += 256) {
    int d = dstI[cb + i];
    int s = srcI[cb + i];
    int b = d >> 9;
    int p = atomicAdd(&cur[b], 1);
    pko[p] = (uint32_t)s | ((uint32_t)(d & 511) << 17);
  }
  __syncthreads();
  for (int b = t; b < NBUCK; b += 256) {
    int c = ex[b + 1] - ex[b];
    gbase[b] = c ? atomicAdd(&bucketCursor[b], c) : 0;
  }
  __syncthreads();
  for (int i = t; i < cc; i += 256) {
    int lo = 0, hi = NBUCK - 1;
    while (lo < hi) { int m = (lo + hi + 1) >> 1; if (ex[m] <= i) lo = m; else hi = m - 1; }
    pairsG[gbase[lo] + (i - ex[lo])] = pko[i];
  }
}

// ---------------- pass B: per-bucket node-level CSR (starts + esrc) ----------------
__global__ __launch_bounds__(256) void kbinB(const uint32_t* __restrict__ pairsG,
                                             const int* __restrict__ bucketStart,
                                             int* __restrict__ starts,
                                             int* __restrict__ esrc) {
  __shared__ int hist[512];
  __shared__ int ex2[512];
  __shared__ int part[256];
  int t = threadIdx.x;
  int b = blockIdx.x;
  int nbase = b << 9;
  int base = bucketStart[b];
  int ecnt = bucketStart[b + 1] - base;

  hist[t] = 0; hist[t + 256] = 0;
  __syncthreads();
  for (int i = t; i < ecnt; i += 256) atomicAdd(&hist[pairsG[base + i] >> 17], 1);
  __syncthreads();
  int a = hist[2 * t], c = hist[2 * t + 1];
  part[t] = a + c;
  __syncthreads();
  for (int d = 1; d < 256; d <<= 1) {
    int u = (t >= d) ? part[t - d] : 0;
    __syncthreads();
    part[t] += u;
    __syncthreads();
  }
  int pex = part[t] - (a + c);
  ex2[2 * t] = pex;
  ex2[2 * t + 1] = pex + a;
  __syncthreads();
  for (int n = t; n < 512; n += 256) {
    int node = nbase + n;
    if (node < NN) starts[node] = base + ex2[n];
  }
  if (b == NBUCK - 1 && t == 0) starts[NN] = EE;
  for (int n = t; n < 512; n += 256) hist[n] = ex2[n];
  __syncthreads();
  for (int i = t; i < ecnt; i += 256) {
    uint32_t p = pairsG[base + i];
    int dl = p >> 17;
    int s = p & 0x1FFFF;
    int lp = atomicAdd(&hist[dl], 1);
    esrc[base + lp] = s;
  }
}

// ---------------- paired CSR gather: half-wave = one row (32 lanes x 4B) ----------------
__global__ __launch_bounds__(256) void kgatherP(const ushort* __restrict__ featb,
                                                const int* __restrict__ starts,
                                                const int* __restrict__ esrc,
                                                ushort* __restrict__ outb) {
  int w = (blockIdx.x * 256 + threadIdx.x) >> 6;  // node
  int l = threadIdx.x & 63;
  if (w >= NN) return;
  int h = l >> 5;        // half id
  int c = l & 31;        // channel pair
  int b = starts[w], e = starts[w + 1];
  float ax = 0.f, ay = 0.f;
  int i = b;
  for (; i + 8 <= e; i += 8) {
    int s0 = esrc[i + h];
    int s1 = esrc[i + 2 + h];
    int s2 = esrc[i + 4 + h];
    int s3 = esrc[i + 6 + h];
    uint32_t u0 = *(const uint32_t*)(featb + (size_t)s0 * 64 + 2 * c);
    uint32_t u1 = *(const uint32_t*)(featb + (size_t)s1 * 64 + 2 * c);
    uint32_t u2 = *(const uint32_t*)(featb + (size_t)s2 * 64 + 2 * c);
    uint32_t u3 = *(const uint32_t*)(featb + (size_t)s3 * 64 + 2 * c);
    ax += bf2f((ushort)u0) + bf2f((ushort)u1) + bf2f((ushort)u2) + bf2f((ushort)u3);
    ay += bf2f((ushort)(u0 >> 16)) + bf2f((ushort)(u1 >> 16)) +
          bf2f((ushort)(u2 >> 16)) + bf2f((ushort)(u3 >> 16));
  }
  for (; i + 2 <= e; i += 2) {
    int s = esrc[i + h];
    uint32_t u = *(const uint32_t*)(featb + (size_t)s * 64 + 2 * c);
    ax += bf2f((ushort)u);
    ay += bf2f((ushort)(u >> 16));
  }
  if (i + h < e) {
    int s = esrc[i + h];
    uint32_t u = *(const uint32_t*)(featb + (size_t)s * 64 + 2 * c);
    ax += bf2f((ushort)u);
    ay += bf2f((ushort)(u >> 16));
  }
  ax += __shfl_xor(ax, 32);
  ay += __shfl_xor(ay, 32);
  if (h == 0) {
    uint32_t o = (uint32_t)f2bf(ax) | ((uint32_t)f2bf(ay) << 16);
    *(uint32_t*)(outb + (size_t)w * 64 + 2 * c) = o;
  }
}

// ---------------- fused MFMA: h1 = relu(agg1@w1rel^T + x@w1root^T + b1);
//                  y = h1@w2rel^T (bf16); r2 = h1@w2root^T (bf16) ----------------
__global__ __launch_bounds__(256) void kfused(const ushort* __restrict__ xb,
                                              const ushort* __restrict__ aggb,
                                              const ushort* __restrict__ WF,
                                              const float* __restrict__ b1,
                                              ushort* __restrict__ y,
                                              ushort* __restrict__ r2b) {
  __shared__ __align__(16) char hT[16384];
  int t = threadIdx.x, l = t & 63, wv = t >> 6;
  int n0 = blockIdx.x * 64 + wv * 16;
  int row = l & 15;
  int kg = l >> 4;
  int nr = n0 + row; if (nr > NN - 1) nr = NN - 1;

  short8 aA[2], aX[2];
  {
    const ushort* ap = aggb + (size_t)nr * 64 + kg * 8;
    aA[0] = *(const short8*)(ap);
    aA[1] = *(const short8*)(ap + 32);
    const ushort* xp = xb + (size_t)nr * 64 + kg * 8;
    aX[0] = *(const short8*)(xp);
    aX[1] = *(const short8*)(xp + 32);
  }

  const ushort* wf1rel = WF;
  const ushort* wf1root = WF + 8192;
  char* basep = hT + wv * 4096;

#pragma unroll
  for (int tt = 0; tt < 8; ++tt) {
    f32x4 acc = {0.f, 0.f, 0.f, 0.f};
#pragma unroll
    for (int s = 0; s < 2; ++s) {
      short8 br = *(const short8*)(wf1rel + ((size_t)(tt * 2 + s) * 64 + l) * 8);
      acc = __builtin_amdgcn_mfma_f32_16x16x32_bf16(aA[s], br, acc, 0, 0, 0);
      short8 bo = *(const short8*)(wf1root + ((size_t)(tt * 2 + s) * 64 + l) * 8);
      acc = __builtin_amdgcn_mfma_f32_16x16x32_bf16(aX[s], bo, acc, 0, 0, 0);
    }
    float bias = b1[tt * 16 + row];
#pragma unroll
    for (int r = 0; r < 4; ++r) {
      float hv = fmaxf(acc[r] + bias, 0.f);
      int nl = kg * 4 + r;
      int off = nl * 256 + (tt * 16 + row) * 2;
      off ^= (nl & 7) << 4;
      *(ushort*)(basep + off) = f2bf(hv);
    }
  }
  __syncthreads();

  short8 aH[4];
#pragma unroll
  for (int s = 0; s < 4; ++s) {
    int off = row * 256 + s * 64 + kg * 16;
    off ^= (row & 7) << 4;
    aH[s] = *(const short8*)(basep + off);
  }

  const ushort* wf2rel = WF + 16384;
  const ushort* wf2root = WF + 24576;
#pragma unroll
  for (int tt = 0; tt < 4; ++tt) {
    f32x4 accY = {0.f, 0.f, 0.f, 0.f};
    f32x4 accR = {0.f, 0.f, 0.f, 0.f};
#pragma unroll
    for (int s = 0; s < 4; ++s) {
      short8 br = *(const short8*)(wf2rel + ((size_t)(tt * 4 + s) * 64 + l) * 8);
      accY = __builtin_amdgcn_mfma_f32_16x16x32_bf16(aH[s], br, accY, 0, 0, 0);
      short8 bo = *(const short8*)(wf2root + ((size_t)(tt * 4 + s) * 64 + l) * 8);
      accR = __builtin_amdgcn_mfma_f32_16x16x32_bf16(aH[s], bo, accR, 0, 0, 0);
    }
#pragma unroll
    for (int r = 0; r < 4; ++r) {
      int nd = n0 + kg * 4 + r;
      if (nd < NN) {
        y[(size_t)nd * 64 + tt * 16 + row] = f2bf(accY[r]);
        r2b[(size_t)nd * 64 + tt * 16 + row] = f2bf(accR[r]);
      }
    }
  }
}

// ---------------- h2 = relu(aggy + r2 + b2); run-length pool (+ graph counts) ----------------
__global__ __launch_bounds__(256) void kpool(const ushort* __restrict__ aggy,
                                             const ushort* __restrict__ r2b,
                                             const float* __restrict__ b2v,
                                             const int* __restrict__ batch,
                                             float* __restrict__ pool,
                                             float* __restrict__ cntg) {
  int t = threadIdx.x, l = t & 63, wv = t >> 6;
  int nstart = blockIdx.x * 256 + wv * 64;
  float bias = b2v[l];
  float acc = 0.f;
  int curg = -1;
  int runlen = 0;
  for (int i = 0; i < 64; ++i) {
    int n = nstart + i;
    if (n >= NN) break;
    int g = __builtin_amdgcn_readfirstlane(batch[n]);
    if (g != curg) {
      if (curg >= 0) {
        atomicAdd(&pool[curg * 64 + l], acc);
        if (l == 0) atomicAdd(&cntg[curg], (float)runlen);
      }
      curg = g;
      acc = 0.f;
      runlen = 0;
    }
    float v = bf2f(aggy[(size_t)n * 64 + l]) + bf2f(r2b[(size_t)n * 64 + l]) + bias;
    acc += fmaxf(v, 0.f);
    ++runlen;
  }
  if (curg >= 0) {
    atomicAdd(&pool[curg * 64 + l], acc);
    if (l == 0) atomicAdd(&cntg[curg], (float)runlen);
  }
}

// ---------------- pooled MLPs: one block per graph, h3 in LDS ----------------
__global__ __launch_bounds__(64) void kfinal2(
    const float* __restrict__ pool, const float* __restrict__ cntg,
    const float* __restrict__ es_w1, const float* __restrict__ es_b1,
    const float* __restrict__ es_w2, const float* __restrict__ es_b2,
    const float* __restrict__ es_w3, const float* __restrict__ es_b3,
    const float* __restrict__ d_w1, const float* __restrict__ d_b1,
    const float* __restrict__ d_w2, const float* __restrict__ d_b2,
    const float* __restrict__ d_w3, const float* __restrict__ d_b3,
    float* __restrict__ out) {
  __shared__ float h3[64];
  __shared__ float z1s[8];
  __shared__ float t2s[8];
  int g = blockIdx.x;
  int l = threadIdx.x;
  float c = fmaxf(cntg[g], 1.f);
  float h = pool[g * 64 + l] / c;
  h3[l] = h;
  out[g * 64 + l] = h;
  __syncthreads();
  if (l < 8) {
    float a = es_b1[l];
#pragma unroll
    for (int k = 0; k < 64; ++k) a += es_w1[l * 64 + k] * h3[k];
    z1s[l] = fmaxf(a, 0.f);
  }
  __syncthreads();
  if (l == 0) {
    float z2[4];
#pragma unroll
    for (int j = 0; j < 4; ++j) {
      float a = es_b2[j];
#pragma unroll
      for (int k = 0; k < 8; ++k) a += es_w2[j * 8 + k] * z1s[k];
      z2[j] = fmaxf(a, 0.f);
    }
    float z = es_b3[0];
#pragma unroll
    for (int k = 0; k < 4; ++k) z += es_w3[k] * z2[k];
    float t1[4];
#pragma unroll
    for (int j = 0; j < 4; ++j) t1[j] = fmaxf(d_w1[j] * z + d_b1[j], 0.f);
#pragma unroll
    for (int j = 0; j < 8; ++j) {
      float a = d_b2[j];
#pragma unroll
      for (int k = 0; k < 4; ++k) a += d_w2[j * 4 + k] * t1[k];
      t2s[j] = fmaxf(a, 0.f);
    }
  }
  __syncthreads();
  float a = d_b3[l];
#pragma unroll
  for (int k = 0; k < 8; ++k) a += d_w3[l * 8 + k] * t2s[k];
  out[4096 + g * 64 + l] = a;
}

extern "C" void kernel_launch(void* const* d_in, const int* in_sizes, int n_in,
                              void* d_out, int out_size, void* d_ws, size_t ws_size,
                              hipStream_t stream) {
  const float* x = (const float*)d_in[0];
  const int* ei = (const int*)d_in[1];
  const int* srcI = ei;
  const int* dstI = ei + EE;
  const int* batch = (const int*)d_in[2];
  const float* w1_rel = (const float*)d_in[3];
  const float* b1_rel = (const float*)d_in[4];
  const float* w1_root = (const float*)d_in[5];
  const float* w2_rel = (const float*)d_in[6];
  const float* b2_rel = (const float*)d_in[7];
  const float* w2_root = (const float*)d_in[8];
  const float* es_w1 = (const float*)d_in[9];
  const float* es_b1 = (const float*)d_in[10];
  const float* es_w2 = (const float*)d_in[11];
  const float* es_b2 = (const float*)d_in[12];
  const float* es_w3 = (const float*)d_in[13];
  const float* es_b3 = (const float*)d_in[14];
  const float* d_w1 = (const float*)d_in[15];
  const float* d_b1 = (const float*)d_in[16];
  const float* d_w2 = (const float*)d_in[17];
  const float* d_b2 = (const float*)d_in[18];
  const float* d_w3 = (const float*)d_in[19];
  const float* d_b3 = (const float*)d_in[20];

  ushort* xb = (ushort*)d_ws;                     // NN*64 bf16
  ushort* aggb = xb + (size_t)NN * 64;            // NN*64 bf16
  ushort* yb = aggb + (size_t)NN * 64;            // NN*64 bf16
  ushort* aggy = yb + (size_t)NN * 64;            // NN*64 bf16
  ushort* r2b = aggy + (size_t)NN * 64;           // NN*64 bf16
  float* pool = (float*)(r2b + (size_t)NN * 64);  // 4096
  float* cntg = pool + 4096;                      // 64
  ushort* WF = (ushort*)(cntg + 64);              // 32768 bf16
  int* starts = (int*)(WF + 32768);               // NN+1
  int* bucketCount = starts + NN + 1;             // NBUCK
  int* bucketStart = bucketCount + NBUCK;         // NBUCK+1
  int* bucketCursor = bucketStart + NBUCK + 1;    // NBUCK
  uint32_t* pairsG = (uint32_t*)(bucketCursor + NBUCK);  // EE
  int* esrc = (int*)(pairsG + EE);                // EE
  float* out = (float*)d_out;

  hipMemsetAsync(pool, 0, (4096 + 64) * 4, stream);
  hipMemsetAsync(bucketCount, 0, NBUCK * 4, stream);
  kprepfrag<<<32, 256, 0, stream>>>(w1_rel, w1_root, w2_rel, w2_root, WF);
  kxcvt<<<(NN * 64 / 4 + 255) / 256, 256, 0, stream>>>(x, xb);
  khist<<<256, 256, 0, stream>>>(dstI, bucketCount);
  kscan196<<<1, 256, 0, stream>>>(bucketCount, bucketStart, bucketCursor);
  kbinA<<<NCHUNK, 256, 0, stream>>>(srcI, dstI, bucketCursor, pairsG);
  kbinB<<<NBUCK, 256, 0, stream>>>(pairsG, bucketStart, starts, esrc);
  kgatherP<<<(NN * 64 + 255) / 256, 256, 0, stream>>>(xb, starts, esrc, aggb);
  kfused<<<(NN + 63) / 64, 256, 0, stream>>>(xb, aggb, WF, b1_rel, yb, r2b);
  kgatherP<<<(NN * 64 + 255) / 256, 256, 0, stream>>>(yb, starts, esrc, aggy);
  kpool<<<(NN + 255) / 256, 256, 0, stream>>>(aggy, r2b, b2_rel, batch, pool, cntg);
  kfinal2<<<64, 64, 0, stream>>>(pool, cntg, es_w1, es_b1, es_w2, es_b2, es_w3, es_b3,
                                 d_w1, d_b1, d_w2, d_b2, d_w3, d_b3, out);
}